// Round 1
// baseline (421.336 us; speedup 1.0000x reference)
//
#include <hip/hip_runtime.h>
#include <math.h>

#define F_DIM 512
#define H_DIM 128
#define C_DIM 40
#define EPS_F 0.3f

// ---------------- CSR build ----------------

__global__ __launch_bounds__(256) void hist_kernel(const int* __restrict__ row,
    const int* __restrict__ col, int* __restrict__ deg_row,
    int* __restrict__ cnt_col, int E) {
  int i = blockIdx.x * 256 + threadIdx.x;
  if (i < E) {
    atomicAdd(&deg_row[row[i]], 1);
    atomicAdd(&cnt_col[col[i]], 1);
  }
}

__global__ __launch_bounds__(256) void scan_partial(const int* __restrict__ cnt,
    int* __restrict__ part, int N) {
  __shared__ int sd[256];
  int t = threadIdx.x;
  int i = blockIdx.x * 256 + t;
  sd[t] = (i < N) ? cnt[i] : 0;
  __syncthreads();
  for (int s = 128; s > 0; s >>= 1) {
    if (t < s) sd[t] += sd[t + s];
    __syncthreads();
  }
  if (t == 0) part[blockIdx.x] = sd[0];
}

// single block exclusive scan of up to 256 partials
__global__ __launch_bounds__(256) void scan_single(int* __restrict__ part, int P) {
  __shared__ int sd[256];
  int t = threadIdx.x;
  sd[t] = (t < P) ? part[t] : 0;
  __syncthreads();
  for (int off = 1; off < 256; off <<= 1) {
    int add = (t >= off) ? sd[t - off] : 0;
    __syncthreads();
    sd[t] += add;
    __syncthreads();
  }
  if (t < P) part[t] = (t == 0) ? 0 : sd[t - 1];
}

__global__ __launch_bounds__(256) void scan_final(const int* __restrict__ cnt,
    const int* __restrict__ part, int* __restrict__ col_ptr,
    const int* __restrict__ deg_row, float* __restrict__ nd, int N, int E) {
  __shared__ int sd[256];
  int t = threadIdx.x;
  int i = blockIdx.x * 256 + t;
  int v = (i < N) ? cnt[i] : 0;
  sd[t] = v;
  __syncthreads();
  for (int off = 1; off < 256; off <<= 1) {
    int add = (t >= off) ? sd[t - off] : 0;
    __syncthreads();
    sd[t] += add;
    __syncthreads();
  }
  if (i < N) {
    int excl = (t == 0) ? 0 : sd[t - 1];
    col_ptr[i] = part[blockIdx.x] + excl;
    int d = deg_row[i];
    nd[i] = 1.0f / sqrtf((float)(d < 1 ? 1 : d));
  }
  if (i == 0) col_ptr[N] = E;
}

__global__ __launch_bounds__(256) void scatter_kernel(const int* __restrict__ row,
    const int* __restrict__ col, const int* __restrict__ col_ptr,
    int* __restrict__ fill, int* __restrict__ csr_src, int E) {
  int e = blockIdx.x * 256 + threadIdx.x;
  if (e < E) {
    int v = col[e];
    int pos = col_ptr[v] + atomicAdd(&fill[v], 1);
    csr_src[pos] = row[e];
  }
}

// ---------------- GEMM1: h0 = relu(x @ t1_w.T + b)  [N,512]x[512,128] ----------------

__global__ __launch_bounds__(256) void gemm1_relu(const float* __restrict__ x,
    const float* __restrict__ w, const float* __restrict__ b,
    float* __restrict__ h, int N) {
  __shared__ float xs[32][68];    // [k][m], padded stride 68 (16B-aligned rows, spread banks)
  __shared__ float ws[32][132];   // [k][c]
  int t = threadIdx.x;
  int m0 = blockIdx.x * 64;
  int tx = t & 31;   // 32 col groups * 4 cols = 128
  int ty = t >> 5;   // 8 row groups * 8 rows = 64
  float acc[8][4];
#pragma unroll
  for (int i = 0; i < 8; ++i)
#pragma unroll
    for (int j = 0; j < 4; ++j) acc[i][j] = 0.f;
  int kv = (t & 7) * 4;  // k sub-offset for loads
  int mi = t >> 3;       // 0..31

  for (int kk = 0; kk < F_DIM; kk += 32) {
    // x tile: 64 rows x 32 k
#pragma unroll
    for (int half = 0; half < 2; ++half) {
      int m = mi + half * 32;
      int row = m0 + m;
      float4 vx = {0.f, 0.f, 0.f, 0.f};
      if (row < N) vx = *(const float4*)&x[(size_t)row * F_DIM + kk + kv];
      xs[kv + 0][m] = vx.x; xs[kv + 1][m] = vx.y;
      xs[kv + 2][m] = vx.z; xs[kv + 3][m] = vx.w;
    }
    // w tile: 128 rows(c) x 32 k
#pragma unroll
    for (int q = 0; q < 4; ++q) {
      int c = mi + q * 32;
      float4 vw = *(const float4*)&w[(size_t)c * F_DIM + kk + kv];
      ws[kv + 0][c] = vw.x; ws[kv + 1][c] = vw.y;
      ws[kv + 2][c] = vw.z; ws[kv + 3][c] = vw.w;
    }
    __syncthreads();
#pragma unroll
    for (int k = 0; k < 32; ++k) {
      float4 wv = *(const float4*)&ws[k][tx * 4];
      float4 xa = *(const float4*)&xs[k][ty * 8];
      float4 xb = *(const float4*)&xs[k][ty * 8 + 4];
      float xr[8] = {xa.x, xa.y, xa.z, xa.w, xb.x, xb.y, xb.z, xb.w};
      float wr[4] = {wv.x, wv.y, wv.z, wv.w};
#pragma unroll
      for (int i = 0; i < 8; ++i)
#pragma unroll
        for (int j = 0; j < 4; ++j)
          acc[i][j] = fmaf(xr[i], wr[j], acc[i][j]);
    }
    __syncthreads();
  }
#pragma unroll
  for (int i = 0; i < 8; ++i) {
    int row = m0 + ty * 8 + i;
    if (row < N) {
      float4 o;
      o.x = fmaxf(acc[i][0] + b[tx * 4 + 0], 0.f);
      o.y = fmaxf(acc[i][1] + b[tx * 4 + 1], 0.f);
      o.z = fmaxf(acc[i][2] + b[tx * 4 + 2], 0.f);
      o.w = fmaxf(acc[i][3] + b[tx * 4 + 3], 0.f);
      *(float4*)&h[(size_t)row * H_DIM + tx * 4] = o;
    }
  }
}

// ---------------- per-node gate scalars: s1 = h.gw1, s2 = h.gw2 + b ----------------

__global__ __launch_bounds__(256) void gate_s(const float* __restrict__ h,
    const float* __restrict__ gwl, const float* __restrict__ gb, int layer,
    float* __restrict__ s1, float* __restrict__ s2, int N) {
  int wid = (blockIdx.x * 256 + threadIdx.x) >> 6;
  int lane = threadIdx.x & 63;
  if (wid >= N) return;
  float2 hv = *(const float2*)&h[(size_t)wid * H_DIM + lane * 2];
  float2 g1 = *(const float2*)&gwl[lane * 2];
  float2 g2 = *(const float2*)&gwl[H_DIM + lane * 2];
  float p1 = hv.x * g1.x + hv.y * g1.y;
  float p2 = hv.x * g2.x + hv.y * g2.y;
  for (int off = 32; off > 0; off >>= 1) {
    p1 += __shfl_xor(p1, off);
    p2 += __shfl_xor(p2, off);
  }
  if (lane == 0) {
    s1[wid] = p1;
    s2[wid] = p2 + gb[layer];
  }
}

// ---------------- aggregation: h_out[v] = EPS*raw[v] + sum_e coef*h[u] ----------------

__global__ __launch_bounds__(256) void agg_kernel(const float* __restrict__ h,
    const float* __restrict__ raw, const float* __restrict__ s1,
    const float* __restrict__ s2pb, const float* __restrict__ nd,
    const int* __restrict__ col_ptr, const int* __restrict__ csr_src,
    float* __restrict__ hout, int N) {
  int wid = (blockIdx.x * 256 + threadIdx.x) >> 6;
  int lane = threadIdx.x & 63;
  if (wid >= N) return;
  int v = wid;
  int p0 = col_ptr[v], p1 = col_ptr[v + 1];
  float s2v = s2pb[v];
  float ndv = nd[v];
  float ax = 0.f, ay = 0.f;
  for (int base = p0; base < p1; base += 64) {
    int idx = base + lane;
    int u = 0;
    float cf = 0.f;
    if (idx < p1) {
      u = csr_src[idx];
      cf = tanhf(s1[u] + s2v) * nd[u] * ndv;
    }
    int cnt = p1 - base;
    if (cnt > 64) cnt = 64;
    int j = 0;
    for (; j + 4 <= cnt; j += 4) {
      int u0 = __shfl(u, j + 0), u1 = __shfl(u, j + 1);
      int u2 = __shfl(u, j + 2), u3 = __shfl(u, j + 3);
      float c0 = __shfl(cf, j + 0), c1 = __shfl(cf, j + 1);
      float c2 = __shfl(cf, j + 2), c3 = __shfl(cf, j + 3);
      float2 h0 = *(const float2*)&h[(size_t)u0 * H_DIM + lane * 2];
      float2 h1 = *(const float2*)&h[(size_t)u1 * H_DIM + lane * 2];
      float2 h2 = *(const float2*)&h[(size_t)u2 * H_DIM + lane * 2];
      float2 h3 = *(const float2*)&h[(size_t)u3 * H_DIM + lane * 2];
      ax += c0 * h0.x + c1 * h1.x + c2 * h2.x + c3 * h3.x;
      ay += c0 * h0.y + c1 * h1.y + c2 * h2.y + c3 * h3.y;
    }
    for (; j < cnt; ++j) {
      int uj = __shfl(u, j);
      float cj = __shfl(cf, j);
      float2 hv = *(const float2*)&h[(size_t)uj * H_DIM + lane * 2];
      ax += cj * hv.x;
      ay += cj * hv.y;
    }
  }
  float2 rv = *(const float2*)&raw[(size_t)v * H_DIM + lane * 2];
  float2 o;
  o.x = EPS_F * rv.x + ax;
  o.y = EPS_F * rv.y + ay;
  *(float2*)&hout[(size_t)v * H_DIM + lane * 2] = o;
}

// ---------------- GEMM2 + log_softmax ----------------

__global__ __launch_bounds__(256) void gemm2_lsm(const float* __restrict__ h,
    const float* __restrict__ w, const float* __restrict__ b,
    float* __restrict__ out, int N) {
  __shared__ float ws[C_DIM][129];   // pad 129 -> (lane+k)%32 banks, <=2-way (free)
  __shared__ float bsh[C_DIM];
  __shared__ float hsm[4][H_DIM];
  int t = threadIdx.x;
  for (int i = t; i < C_DIM * H_DIM; i += 256) ws[i / H_DIM][i % H_DIM] = w[i];
  if (t < C_DIM) bsh[t] = b[t];
  __syncthreads();
  int wave = t >> 6, lane = t & 63;
  for (int vb = blockIdx.x * 4; vb < N; vb += gridDim.x * 4) {  // block-uniform loop
    int v = vb + wave;
    bool act = v < N;
    if (act) {
      float2 hv = *(const float2*)&h[(size_t)v * H_DIM + lane * 2];
      hsm[wave][lane * 2] = hv.x;
      hsm[wave][lane * 2 + 1] = hv.y;
    }
    __syncthreads();
    float acc = 0.f;
    if (act && lane < C_DIM) {
#pragma unroll 8
      for (int k = 0; k < H_DIM; ++k)
        acc = fmaf(hsm[wave][k], ws[lane][k], acc);
      acc += bsh[lane];
    }
    float m = (lane < C_DIM) ? acc : -1e30f;
    for (int off = 32; off > 0; off >>= 1) m = fmaxf(m, __shfl_xor(m, off));
    float ex = (lane < C_DIM) ? expf(acc - m) : 0.f;
    float s = ex;
    for (int off = 32; off > 0; off >>= 1) s += __shfl_xor(s, off);
    float lse = m + logf(s);
    if (act && lane < C_DIM) out[(size_t)v * C_DIM + lane] = acc - lse;
    __syncthreads();
  }
}

// ---------------- launch ----------------

extern "C" void kernel_launch(void* const* d_in, const int* in_sizes, int n_in,
                              void* d_out, int out_size, void* d_ws, size_t ws_size,
                              hipStream_t stream) {
  const float* x   = (const float*)d_in[0];
  const float* t1w = (const float*)d_in[1];
  const float* t1b = (const float*)d_in[2];
  const float* t2w = (const float*)d_in[3];
  const float* t2b = (const float*)d_in[4];
  const float* gw  = (const float*)d_in[5];   // [2][256]
  const float* gb  = (const float*)d_in[6];   // [2]
  const int*   ei  = (const int*)d_in[7];     // [2][E]
  const int N = in_sizes[0] / F_DIM;
  const int E = in_sizes[7] / 2;
  float* out = (float*)d_out;

  char* p = (char*)d_ws;
  auto take = [&](size_t bytes) {
    char* r = p;
    p += (bytes + 255) & ~(size_t)255;
    return r;
  };
  float* h0 = (float*)take((size_t)N * H_DIM * 4);
  float* h1 = (float*)take((size_t)N * H_DIM * 4);
  float* h2 = (float*)take((size_t)N * H_DIM * 4);
  float* s1 = (float*)take((size_t)N * 4);
  float* s2 = (float*)take((size_t)N * 4);
  float* nd = (float*)take((size_t)N * 4);
  int* cnts = (int*)take((size_t)3 * N * 4);  // deg_row | cnt_col | fill
  int* deg_row = cnts;
  int* cnt_col = cnts + N;
  int* fill    = cnts + 2 * N;
  int* col_ptr = (int*)take((size_t)(N + 1) * 4);
  int* part    = (int*)take(256 * 4);
  int* csr_src = (int*)take((size_t)E * 4);

  const int* row = ei;
  const int* col = ei + E;

  hipMemsetAsync(cnts, 0, (size_t)3 * N * 4, stream);
  int ebl = (E + 255) / 256;
  hist_kernel<<<ebl, 256, 0, stream>>>(row, col, deg_row, cnt_col, E);
  int NB = (N + 255) / 256;  // 196 for N=50000, must be <=256
  scan_partial<<<NB, 256, 0, stream>>>(cnt_col, part, N);
  scan_single<<<1, 256, 0, stream>>>(part, NB);
  scan_final<<<NB, 256, 0, stream>>>(cnt_col, part, col_ptr, deg_row, nd, N, E);
  scatter_kernel<<<ebl, 256, 0, stream>>>(row, col, col_ptr, fill, csr_src, E);

  gemm1_relu<<<(N + 63) / 64, 256, 0, stream>>>(x, t1w, t1b, h0, N);

  int nwb = (N + 3) / 4;  // one wave per node, 4 nodes per 256-thread block
  gate_s<<<nwb, 256, 0, stream>>>(h0, gw + 0 * 2 * H_DIM, gb, 0, s1, s2, N);
  agg_kernel<<<nwb, 256, 0, stream>>>(h0, h0, s1, s2, nd, col_ptr, csr_src, h1, N);
  gate_s<<<nwb, 256, 0, stream>>>(h1, gw + 1 * 2 * H_DIM, gb, 1, s1, s2, N);
  agg_kernel<<<nwb, 256, 0, stream>>>(h1, h0, s1, s2, nd, col_ptr, csr_src, h2, N);

  gemm2_lsm<<<1024, 256, 0, stream>>>(h2, t2w, t2b, out, N);
}

// Round 2
// 333.858 us; speedup vs baseline: 1.2620x; 1.2620x over previous
//
#include <hip/hip_runtime.h>
#include <math.h>

#define F_DIM 512
#define H_DIM 128
#define C_DIM 40
#define EPS_F 0.3f

typedef float f32x4 __attribute__((ext_vector_type(4)));
typedef unsigned int u32x4 __attribute__((ext_vector_type(4)));
typedef __bf16 bf16x8 __attribute__((ext_vector_type(8)));

// ---------------- CSR build ----------------

__global__ __launch_bounds__(256) void hist_kernel(const int* __restrict__ row,
    const int* __restrict__ col, int* __restrict__ deg_row,
    int* __restrict__ cnt_col, int E) {
  int i = blockIdx.x * 256 + threadIdx.x;
  if (i < E) {
    atomicAdd(&deg_row[row[i]], 1);
    atomicAdd(&cnt_col[col[i]], 1);
  }
}

__global__ __launch_bounds__(256) void scan_partial(const int* __restrict__ cnt,
    int* __restrict__ part, int N) {
  __shared__ int sd[256];
  int t = threadIdx.x;
  int i = blockIdx.x * 256 + t;
  sd[t] = (i < N) ? cnt[i] : 0;
  __syncthreads();
  for (int s = 128; s > 0; s >>= 1) {
    if (t < s) sd[t] += sd[t + s];
    __syncthreads();
  }
  if (t == 0) part[blockIdx.x] = sd[0];
}

__global__ __launch_bounds__(256) void scan_single(int* __restrict__ part, int P) {
  __shared__ int sd[256];
  int t = threadIdx.x;
  sd[t] = (t < P) ? part[t] : 0;
  __syncthreads();
  for (int off = 1; off < 256; off <<= 1) {
    int add = (t >= off) ? sd[t - off] : 0;
    __syncthreads();
    sd[t] += add;
    __syncthreads();
  }
  if (t < P) part[t] = (t == 0) ? 0 : sd[t - 1];
}

__global__ __launch_bounds__(256) void scan_final(const int* __restrict__ cnt,
    const int* __restrict__ part, int* __restrict__ col_ptr,
    const int* __restrict__ deg_row, float* __restrict__ nd, int N, int E) {
  __shared__ int sd[256];
  int t = threadIdx.x;
  int i = blockIdx.x * 256 + t;
  int v = (i < N) ? cnt[i] : 0;
  sd[t] = v;
  __syncthreads();
  for (int off = 1; off < 256; off <<= 1) {
    int add = (t >= off) ? sd[t - off] : 0;
    __syncthreads();
    sd[t] += add;
    __syncthreads();
  }
  if (i < N) {
    int excl = (t == 0) ? 0 : sd[t - 1];
    col_ptr[i] = part[blockIdx.x] + excl;
    int d = deg_row[i];
    nd[i] = 1.0f / sqrtf((float)(d < 1 ? 1 : d));
  }
  if (i == 0) col_ptr[N] = E;
}

__global__ __launch_bounds__(256) void scatter_kernel(const int* __restrict__ row,
    const int* __restrict__ col, const int* __restrict__ col_ptr,
    int* __restrict__ fill, int* __restrict__ csr_src, int E) {
  int e = blockIdx.x * 256 + threadIdx.x;
  if (e < E) {
    int v = col[e];
    int pos = col_ptr[v] + atomicAdd(&fill[v], 1);
    csr_src[pos] = row[e];
  }
}

// ---------------- GEMM1 (bf16 MFMA): h0 = relu(x @ t1_w.T + b) ----------------
// BM=64, BN=128(=H), BK=64. 4 waves as 2x2, each wave 32x64 (M_rep=2,N_rep=4).
// LDS tiles bf16, [row][k] with 16B-chunk XOR swizzle: chunk' = kc ^ (row&7).

__device__ inline unsigned int pack2bf(float a, float b) {
  unsigned int ua = __builtin_bit_cast(unsigned int, a);
  unsigned int ub = __builtin_bit_cast(unsigned int, b);
  ua = (ua + 0x7fffu + ((ua >> 16) & 1u)) >> 16;
  ub = (ub + 0x7fffu + ((ub >> 16) & 1u)) >> 16;
  return ua | (ub << 16);
}

__global__ __launch_bounds__(256) void gemm1_mfma(const float* __restrict__ x,
    const float* __restrict__ w, const float* __restrict__ b,
    float* __restrict__ h, int N) {
  __shared__ u32x4 AsBuf[512];    // 64 rows * 128 B (8 chunks of 16B)
  __shared__ u32x4 BsBuf[1024];   // 128 rows * 128 B
  char* Asc = (char*)AsBuf;
  char* Bsc = (char*)BsBuf;

  int t = threadIdx.x;
  int lane = t & 63;
  int wid = t >> 6;
  int wm = wid >> 1;   // 0..1 : 32-row slab
  int wn = wid & 1;    // 0..1 : 64-col slab
  int m0 = blockIdx.x * 64;

  f32x4 acc[2][4];
#pragma unroll
  for (int i = 0; i < 2; ++i)
#pragma unroll
    for (int j = 0; j < 4; ++j) acc[i][j] = (f32x4){0.f, 0.f, 0.f, 0.f};

  float bias[4];
#pragma unroll
  for (int j = 0; j < 4; ++j) bias[j] = b[wn * 64 + j * 16 + (lane & 15)];

  for (int kk = 0; kk < F_DIM; kk += 64) {
    // stage A: 64x64 = 512 chunks of 8 bf16 (16B each); 2 per thread
#pragma unroll
    for (int q = 0; q < 2; ++q) {
      int c = q * 256 + t;
      int row = c >> 3, kc = c & 7;
      int gm = m0 + row;
      f32x4 v0 = {0.f, 0.f, 0.f, 0.f}, v1 = {0.f, 0.f, 0.f, 0.f};
      if (gm < N) {
        const float* src = &x[(size_t)gm * F_DIM + kk + kc * 8];
        v0 = *(const f32x4*)src;
        v1 = *(const f32x4*)(src + 4);
      }
      u32x4 pk;
      pk[0] = pack2bf(v0[0], v0[1]);
      pk[1] = pack2bf(v0[2], v0[3]);
      pk[2] = pack2bf(v1[0], v1[1]);
      pk[3] = pack2bf(v1[2], v1[3]);
      *(u32x4*)(Asc + row * 128 + ((kc ^ (row & 7)) << 4)) = pk;
    }
    // stage B: 128x64 = 1024 chunks; 4 per thread
#pragma unroll
    for (int q = 0; q < 4; ++q) {
      int c = q * 256 + t;
      int row = c >> 3, kc = c & 7;
      const float* src = &w[(size_t)row * F_DIM + kk + kc * 8];
      f32x4 v0 = *(const f32x4*)src;
      f32x4 v1 = *(const f32x4*)(src + 4);
      u32x4 pk;
      pk[0] = pack2bf(v0[0], v0[1]);
      pk[1] = pack2bf(v0[2], v0[3]);
      pk[2] = pack2bf(v1[0], v1[1]);
      pk[3] = pack2bf(v1[2], v1[3]);
      *(u32x4*)(Bsc + row * 128 + ((kc ^ (row & 7)) << 4)) = pk;
    }
    __syncthreads();
#pragma unroll
    for (int kh = 0; kh < 2; ++kh) {
      bf16x8 af[2], bfr[4];
      int kc = kh * 4 + (lane >> 4);
#pragma unroll
      for (int i = 0; i < 2; ++i) {
        int row = wm * 32 + i * 16 + (lane & 15);
        af[i] = *(const bf16x8*)(Asc + row * 128 + ((kc ^ (row & 7)) << 4));
      }
#pragma unroll
      for (int j = 0; j < 4; ++j) {
        int row = wn * 64 + j * 16 + (lane & 15);
        bfr[j] = *(const bf16x8*)(Bsc + row * 128 + ((kc ^ (row & 7)) << 4));
      }
#pragma unroll
      for (int i = 0; i < 2; ++i)
#pragma unroll
        for (int j = 0; j < 4; ++j)
          acc[i][j] = __builtin_amdgcn_mfma_f32_16x16x32_bf16(af[i], bfr[j], acc[i][j], 0, 0, 0);
    }
    __syncthreads();
  }

  // epilogue: C/D layout col=lane&15, row=(lane>>4)*4+reg  [m89/m91 verified]
#pragma unroll
  for (int i = 0; i < 2; ++i)
#pragma unroll
    for (int j = 0; j < 4; ++j) {
      int col = wn * 64 + j * 16 + (lane & 15);
      int rbase = m0 + wm * 32 + i * 16 + ((lane >> 4) * 4);
#pragma unroll
      for (int r = 0; r < 4; ++r) {
        int gr = rbase + r;
        if (gr < N) h[(size_t)gr * H_DIM + col] = fmaxf(acc[i][j][r] + bias[j], 0.f);
      }
    }
}

// ---------------- per-node gate scalars ----------------

__global__ __launch_bounds__(256) void gate_s(const float* __restrict__ h,
    const float* __restrict__ gwl, const float* __restrict__ gb, int layer,
    float* __restrict__ s1, float* __restrict__ s2, int N) {
  int wid = (blockIdx.x * 256 + threadIdx.x) >> 6;
  int lane = threadIdx.x & 63;
  if (wid >= N) return;
  float2 hv = *(const float2*)&h[(size_t)wid * H_DIM + lane * 2];
  float2 g1 = *(const float2*)&gwl[lane * 2];
  float2 g2 = *(const float2*)&gwl[H_DIM + lane * 2];
  float p1 = hv.x * g1.x + hv.y * g1.y;
  float p2 = hv.x * g2.x + hv.y * g2.y;
  for (int off = 32; off > 0; off >>= 1) {
    p1 += __shfl_xor(p1, off);
    p2 += __shfl_xor(p2, off);
  }
  if (lane == 0) {
    s1[wid] = p1;
    s2[wid] = p2 + gb[layer];
  }
}

// ---------------- aggregation ----------------

__global__ __launch_bounds__(256) void agg_kernel(const float* __restrict__ h,
    const float* __restrict__ raw, const float* __restrict__ s1,
    const float* __restrict__ s2pb, const float* __restrict__ nd,
    const int* __restrict__ col_ptr, const int* __restrict__ csr_src,
    float* __restrict__ hout, int N) {
  int wid = (blockIdx.x * 256 + threadIdx.x) >> 6;
  int lane = threadIdx.x & 63;
  if (wid >= N) return;
  int v = wid;
  int p0 = col_ptr[v], p1 = col_ptr[v + 1];
  float s2v = s2pb[v];
  float ndv = nd[v];
  float ax = 0.f, ay = 0.f;
  for (int base = p0; base < p1; base += 64) {
    int idx = base + lane;
    int u = 0;
    float cf = 0.f;
    if (idx < p1) {
      u = csr_src[idx];
      cf = tanhf(s1[u] + s2v) * nd[u] * ndv;
    }
    int cnt = p1 - base;
    if (cnt > 64) cnt = 64;
    int j = 0;
    for (; j + 4 <= cnt; j += 4) {
      int u0 = __shfl(u, j + 0), u1 = __shfl(u, j + 1);
      int u2 = __shfl(u, j + 2), u3 = __shfl(u, j + 3);
      float c0 = __shfl(cf, j + 0), c1 = __shfl(cf, j + 1);
      float c2 = __shfl(cf, j + 2), c3 = __shfl(cf, j + 3);
      float2 h0 = *(const float2*)&h[(size_t)u0 * H_DIM + lane * 2];
      float2 h1 = *(const float2*)&h[(size_t)u1 * H_DIM + lane * 2];
      float2 h2 = *(const float2*)&h[(size_t)u2 * H_DIM + lane * 2];
      float2 h3 = *(const float2*)&h[(size_t)u3 * H_DIM + lane * 2];
      ax += c0 * h0.x + c1 * h1.x + c2 * h2.x + c3 * h3.x;
      ay += c0 * h0.y + c1 * h1.y + c2 * h2.y + c3 * h3.y;
    }
    for (; j < cnt; ++j) {
      int uj = __shfl(u, j);
      float cj = __shfl(cf, j);
      float2 hv = *(const float2*)&h[(size_t)uj * H_DIM + lane * 2];
      ax += cj * hv.x;
      ay += cj * hv.y;
    }
  }
  float2 rv = *(const float2*)&raw[(size_t)v * H_DIM + lane * 2];
  float2 o;
  o.x = EPS_F * rv.x + ax;
  o.y = EPS_F * rv.y + ay;
  *(float2*)&hout[(size_t)v * H_DIM + lane * 2] = o;
}

// ---------------- GEMM2 + log_softmax ----------------

__global__ __launch_bounds__(256) void gemm2_lsm(const float* __restrict__ h,
    const float* __restrict__ w, const float* __restrict__ b,
    float* __restrict__ out, int N) {
  __shared__ float ws[C_DIM][129];
  __shared__ float bsh[C_DIM];
  __shared__ float hsm[4][H_DIM];
  int t = threadIdx.x;
  for (int i = t; i < C_DIM * H_DIM; i += 256) ws[i / H_DIM][i % H_DIM] = w[i];
  if (t < C_DIM) bsh[t] = b[t];
  __syncthreads();
  int wave = t >> 6, lane = t & 63;
  for (int vb = blockIdx.x * 4; vb < N; vb += gridDim.x * 4) {
    int v = vb + wave;
    bool act = v < N;
    if (act) {
      float2 hv = *(const float2*)&h[(size_t)v * H_DIM + lane * 2];
      hsm[wave][lane * 2] = hv.x;
      hsm[wave][lane * 2 + 1] = hv.y;
    }
    __syncthreads();
    float acc = 0.f;
    if (act && lane < C_DIM) {
#pragma unroll 8
      for (int k = 0; k < H_DIM; ++k)
        acc = fmaf(hsm[wave][k], ws[lane][k], acc);
      acc += bsh[lane];
    }
    float m = (lane < C_DIM) ? acc : -1e30f;
    for (int off = 32; off > 0; off >>= 1) m = fmaxf(m, __shfl_xor(m, off));
    float ex = (lane < C_DIM) ? expf(acc - m) : 0.f;
    float s = ex;
    for (int off = 32; off > 0; off >>= 1) s += __shfl_xor(s, off);
    float lse = m + logf(s);
    if (act && lane < C_DIM) out[(size_t)v * C_DIM + lane] = acc - lse;
    __syncthreads();
  }
}

// ---------------- launch ----------------

extern "C" void kernel_launch(void* const* d_in, const int* in_sizes, int n_in,
                              void* d_out, int out_size, void* d_ws, size_t ws_size,
                              hipStream_t stream) {
  const float* x   = (const float*)d_in[0];
  const float* t1w = (const float*)d_in[1];
  const float* t1b = (const float*)d_in[2];
  const float* t2w = (const float*)d_in[3];
  const float* t2b = (const float*)d_in[4];
  const float* gw  = (const float*)d_in[5];
  const float* gb  = (const float*)d_in[6];
  const int*   ei  = (const int*)d_in[7];
  const int N = in_sizes[0] / F_DIM;
  const int E = in_sizes[7] / 2;
  float* out = (float*)d_out;

  char* p = (char*)d_ws;
  auto take = [&](size_t bytes) {
    char* r = p;
    p += (bytes + 255) & ~(size_t)255;
    return r;
  };
  float* h0 = (float*)take((size_t)N * H_DIM * 4);
  float* h1 = (float*)take((size_t)N * H_DIM * 4);
  float* h2 = (float*)take((size_t)N * H_DIM * 4);
  float* s1 = (float*)take((size_t)N * 4);
  float* s2 = (float*)take((size_t)N * 4);
  float* nd = (float*)take((size_t)N * 4);
  int* cnts = (int*)take((size_t)3 * N * 4);
  int* deg_row = cnts;
  int* cnt_col = cnts + N;
  int* fill    = cnts + 2 * N;
  int* col_ptr = (int*)take((size_t)(N + 1) * 4);
  int* part    = (int*)take(256 * 4);
  int* csr_src = (int*)take((size_t)E * 4);

  const int* row = ei;
  const int* col = ei + E;

  hipMemsetAsync(cnts, 0, (size_t)3 * N * 4, stream);
  int ebl = (E + 255) / 256;
  hist_kernel<<<ebl, 256, 0, stream>>>(row, col, deg_row, cnt_col, E);
  int NB = (N + 255) / 256;
  scan_partial<<<NB, 256, 0, stream>>>(cnt_col, part, N);
  scan_single<<<1, 256, 0, stream>>>(part, NB);
  scan_final<<<NB, 256, 0, stream>>>(cnt_col, part, col_ptr, deg_row, nd, N, E);
  scatter_kernel<<<ebl, 256, 0, stream>>>(row, col, col_ptr, fill, csr_src, E);

  gemm1_mfma<<<(N + 63) / 64, 256, 0, stream>>>(x, t1w, t1b, h0, N);

  int nwb = (N + 3) / 4;
  gate_s<<<nwb, 256, 0, stream>>>(h0, gw + 0 * 2 * H_DIM, gb, 0, s1, s2, N);
  agg_kernel<<<nwb, 256, 0, stream>>>(h0, h0, s1, s2, nd, col_ptr, csr_src, h1, N);
  gate_s<<<nwb, 256, 0, stream>>>(h1, gw + 1 * 2 * H_DIM, gb, 1, s1, s2, N);
  agg_kernel<<<nwb, 256, 0, stream>>>(h1, h0, s1, s2, nd, col_ptr, csr_src, h2, N);

  gemm2_lsm<<<1024, 256, 0, stream>>>(h2, t2w, t2b, out, N);
}

// Round 3
// 265.225 us; speedup vs baseline: 1.5886x; 1.2588x over previous
//
#include <hip/hip_runtime.h>
#include <math.h>

#define F_DIM 512
#define H_DIM 128
#define C_DIM 40
#define EPS_F 0.3f
#define NBLK 160   // partition blocks (keeps scan <= 256 blocks for nbkt<=204)

typedef float f32x4 __attribute__((ext_vector_type(4)));
typedef unsigned int u32x4 __attribute__((ext_vector_type(4)));
typedef __bf16 bf16x8 __attribute__((ext_vector_type(8)));
typedef unsigned long long u64;

// ---------------- CSR build, no global atomics ----------------
// Buckets: node>>8 (nbkt = ceil(N/256) <= 256). All atomics are LDS-scope.

__global__ __launch_bounds__(256) void part_count(const int* __restrict__ row,
    const int* __restrict__ col, int* __restrict__ blkhist, int E, int nbkt, int chunk) {
  __shared__ int ch[256], rh[256];
  int t = threadIdx.x, b = blockIdx.x;
  ch[t] = 0; rh[t] = 0;
  __syncthreads();
  int s = b * chunk, e = min(E, s + chunk);
  for (int i = s + t; i < e; i += 256) {
    atomicAdd(&ch[((unsigned)col[i]) >> 8], 1);
    atomicAdd(&rh[((unsigned)row[i]) >> 8], 1);
  }
  __syncthreads();
  if (t < nbkt) {
    blkhist[t * NBLK + b] = ch[t];
    blkhist[nbkt * NBLK + t * NBLK + b] = rh[t];
  }
}

__global__ __launch_bounds__(256) void scan_partial(const int* __restrict__ cnt,
    int* __restrict__ part, int M) {
  __shared__ int sd[256];
  int t = threadIdx.x;
  int i = blockIdx.x * 256 + t;
  sd[t] = (i < M) ? cnt[i] : 0;
  __syncthreads();
  for (int s = 128; s > 0; s >>= 1) {
    if (t < s) sd[t] += sd[t + s];
    __syncthreads();
  }
  if (t == 0) part[blockIdx.x] = sd[0];
}

__global__ __launch_bounds__(256) void scan_single(int* __restrict__ part, int P) {
  __shared__ int sd[256];
  int t = threadIdx.x;
  sd[t] = (t < P) ? part[t] : 0;
  __syncthreads();
  for (int off = 1; off < 256; off <<= 1) {
    int add = (t >= off) ? sd[t - off] : 0;
    __syncthreads();
    sd[t] += add;
    __syncthreads();
  }
  if (t < P) part[t] = (t == 0) ? 0 : sd[t - 1];
}

__global__ __launch_bounds__(256) void scan_apply(const int* __restrict__ cnt,
    const int* __restrict__ part, int* __restrict__ sc, int M) {
  __shared__ int sd[256];
  int t = threadIdx.x;
  int i = blockIdx.x * 256 + t;
  int v = (i < M) ? cnt[i] : 0;
  sd[t] = v;
  __syncthreads();
  for (int off = 1; off < 256; off <<= 1) {
    int add = (t >= off) ? sd[t - off] : 0;
    __syncthreads();
    sd[t] += add;
    __syncthreads();
  }
  if (i < M) {
    int excl = (t == 0) ? 0 : sd[t - 1];
    sc[i] = part[blockIdx.x] + excl;
  }
}

__global__ __launch_bounds__(256) void part_scatter(const int* __restrict__ row,
    const int* __restrict__ col, const int* __restrict__ sc,
    u64* __restrict__ colpart, int* __restrict__ rowpart, int E, int nbkt, int chunk) {
  __shared__ int cbase[256], rbase[256], coff[256], roff[256];
  int t = threadIdx.x, b = blockIdx.x;
  if (t < nbkt) {
    cbase[t] = sc[t * NBLK + b];
    rbase[t] = sc[nbkt * NBLK + t * NBLK + b] - E;
  }
  coff[t] = 0; roff[t] = 0;
  __syncthreads();
  int s = b * chunk, e = min(E, s + chunk);
  for (int i = s + t; i < e; i += 256) {
    unsigned c = (unsigned)col[i], r = (unsigned)row[i];
    int pc = cbase[c >> 8] + atomicAdd(&coff[c >> 8], 1);
    colpart[pc] = ((u64)r << 32) | (u64)c;
    int pr = rbase[r >> 8] + atomicAdd(&roff[r >> 8], 1);
    rowpart[pr] = (int)r;
  }
}

// one block per bucket: counting-sort by low byte -> col_ptr + csr_src
__global__ __launch_bounds__(256) void bucket_csr(const u64* __restrict__ colpart,
    const int* __restrict__ sc, int* __restrict__ col_ptr, int* __restrict__ csr_src,
    int N, int E, int nbkt) {
  __shared__ int cnt[256], ex[256], off[256];
  int t = threadIdx.x, bkt = blockIdx.x;
  int s = sc[bkt * NBLK];
  int e = sc[(bkt + 1) * NBLK];  // bkt==nbkt-1 reads sc[nbkt*NBLK] == E (row-section start)
  cnt[t] = 0; off[t] = 0;
  __syncthreads();
  for (int i = s + t; i < e; i += 256)
    atomicAdd(&cnt[(int)(colpart[i] & 255u)], 1);
  __syncthreads();
  ex[t] = cnt[t];
  __syncthreads();
  for (int o = 1; o < 256; o <<= 1) {
    int v = (t >= o) ? ex[t - o] : 0;
    __syncthreads();
    ex[t] += v;
    __syncthreads();
  }
  int excl = (t == 0) ? 0 : ex[t - 1];
  __syncthreads();
  ex[t] = excl;
  __syncthreads();
  int node = bkt * 256 + t;
  if (node < N) col_ptr[node] = s + ex[t];
  if (bkt == 0 && t == 0) col_ptr[N] = E;
  for (int i = s + t; i < e; i += 256) {
    u64 p = colpart[i];
    int lb = (int)(p & 255u);
    int dst = s + ex[lb] + atomicAdd(&off[lb], 1);
    csr_src[dst] = (int)(p >> 32);
  }
}

__global__ __launch_bounds__(256) void bucket_deg(const int* __restrict__ rowpart,
    const int* __restrict__ sc, float* __restrict__ nd, int N, int E, int nbkt) {
  __shared__ int cnt[256];
  int t = threadIdx.x, bkt = blockIdx.x;
  int s = sc[nbkt * NBLK + bkt * NBLK] - E;
  int e = (bkt < nbkt - 1) ? (sc[nbkt * NBLK + (bkt + 1) * NBLK] - E) : E;
  cnt[t] = 0;
  __syncthreads();
  for (int i = s + t; i < e; i += 256)
    atomicAdd(&cnt[rowpart[i] & 255], 1);
  __syncthreads();
  int node = bkt * 256 + t;
  if (node < N) {
    int d = cnt[t] < 1 ? 1 : cnt[t];
    nd[node] = 1.0f / sqrtf((float)d);
  }
}

// ---------------- GEMM1 (bf16 MFMA): h0 = relu(x @ t1_w.T + b) ----------------

__device__ inline unsigned int pack2bf(float a, float b) {
  unsigned int ua = __builtin_bit_cast(unsigned int, a);
  unsigned int ub = __builtin_bit_cast(unsigned int, b);
  ua = (ua + 0x7fffu + ((ua >> 16) & 1u)) >> 16;
  ub = (ub + 0x7fffu + ((ub >> 16) & 1u)) >> 16;
  return ua | (ub << 16);
}

__global__ __launch_bounds__(256) void gemm1_mfma(const float* __restrict__ x,
    const float* __restrict__ w, const float* __restrict__ b,
    float* __restrict__ h, int N) {
  __shared__ u32x4 AsBuf[512];
  __shared__ u32x4 BsBuf[1024];
  char* Asc = (char*)AsBuf;
  char* Bsc = (char*)BsBuf;

  int t = threadIdx.x;
  int lane = t & 63;
  int wid = t >> 6;
  int wm = wid >> 1;
  int wn = wid & 1;
  int m0 = blockIdx.x * 64;

  f32x4 acc[2][4];
#pragma unroll
  for (int i = 0; i < 2; ++i)
#pragma unroll
    for (int j = 0; j < 4; ++j) acc[i][j] = (f32x4){0.f, 0.f, 0.f, 0.f};

  float bias[4];
#pragma unroll
  for (int j = 0; j < 4; ++j) bias[j] = b[wn * 64 + j * 16 + (lane & 15)];

  for (int kk = 0; kk < F_DIM; kk += 64) {
#pragma unroll
    for (int q = 0; q < 2; ++q) {
      int c = q * 256 + t;
      int row = c >> 3, kc = c & 7;
      int gm = m0 + row;
      f32x4 v0 = {0.f, 0.f, 0.f, 0.f}, v1 = {0.f, 0.f, 0.f, 0.f};
      if (gm < N) {
        const float* src = &x[(size_t)gm * F_DIM + kk + kc * 8];
        v0 = *(const f32x4*)src;
        v1 = *(const f32x4*)(src + 4);
      }
      u32x4 pk;
      pk[0] = pack2bf(v0[0], v0[1]);
      pk[1] = pack2bf(v0[2], v0[3]);
      pk[2] = pack2bf(v1[0], v1[1]);
      pk[3] = pack2bf(v1[2], v1[3]);
      *(u32x4*)(Asc + row * 128 + ((kc ^ (row & 7)) << 4)) = pk;
    }
#pragma unroll
    for (int q = 0; q < 4; ++q) {
      int c = q * 256 + t;
      int row = c >> 3, kc = c & 7;
      const float* src = &w[(size_t)row * F_DIM + kk + kc * 8];
      f32x4 v0 = *(const f32x4*)src;
      f32x4 v1 = *(const f32x4*)(src + 4);
      u32x4 pk;
      pk[0] = pack2bf(v0[0], v0[1]);
      pk[1] = pack2bf(v0[2], v0[3]);
      pk[2] = pack2bf(v1[0], v1[1]);
      pk[3] = pack2bf(v1[2], v1[3]);
      *(u32x4*)(Bsc + row * 128 + ((kc ^ (row & 7)) << 4)) = pk;
    }
    __syncthreads();
#pragma unroll
    for (int kh = 0; kh < 2; ++kh) {
      bf16x8 af[2], bfr[4];
      int kc = kh * 4 + (lane >> 4);
#pragma unroll
      for (int i = 0; i < 2; ++i) {
        int row = wm * 32 + i * 16 + (lane & 15);
        af[i] = *(const bf16x8*)(Asc + row * 128 + ((kc ^ (row & 7)) << 4));
      }
#pragma unroll
      for (int j = 0; j < 4; ++j) {
        int row = wn * 64 + j * 16 + (lane & 15);
        bfr[j] = *(const bf16x8*)(Bsc + row * 128 + ((kc ^ (row & 7)) << 4));
      }
#pragma unroll
      for (int i = 0; i < 2; ++i)
#pragma unroll
        for (int j = 0; j < 4; ++j)
          acc[i][j] = __builtin_amdgcn_mfma_f32_16x16x32_bf16(af[i], bfr[j], acc[i][j], 0, 0, 0);
    }
    __syncthreads();
  }

#pragma unroll
  for (int i = 0; i < 2; ++i)
#pragma unroll
    for (int j = 0; j < 4; ++j) {
      int col = wn * 64 + j * 16 + (lane & 15);
      int rbase = m0 + wm * 32 + i * 16 + ((lane >> 4) * 4);
#pragma unroll
      for (int r = 0; r < 4; ++r) {
        int gr = rbase + r;
        if (gr < N) h[(size_t)gr * H_DIM + col] = fmaxf(acc[i][j][r] + bias[j], 0.f);
      }
    }
}

// ---------------- per-node gate scalars ----------------

__global__ __launch_bounds__(256) void gate_s(const float* __restrict__ h,
    const float* __restrict__ gwl, const float* __restrict__ gb, int layer,
    float* __restrict__ s1, float* __restrict__ s2, int N) {
  int wid = (blockIdx.x * 256 + threadIdx.x) >> 6;
  int lane = threadIdx.x & 63;
  if (wid >= N) return;
  float2 hv = *(const float2*)&h[(size_t)wid * H_DIM + lane * 2];
  float2 g1 = *(const float2*)&gwl[lane * 2];
  float2 g2 = *(const float2*)&gwl[H_DIM + lane * 2];
  float p1 = hv.x * g1.x + hv.y * g1.y;
  float p2 = hv.x * g2.x + hv.y * g2.y;
  for (int off = 32; off > 0; off >>= 1) {
    p1 += __shfl_xor(p1, off);
    p2 += __shfl_xor(p2, off);
  }
  if (lane == 0) {
    s1[wid] = p1;
    s2[wid] = p2 + gb[layer];
  }
}

// ---------------- aggregation ----------------

__global__ __launch_bounds__(256) void agg_kernel(const float* __restrict__ h,
    const float* __restrict__ raw, const float* __restrict__ s1,
    const float* __restrict__ s2pb, const float* __restrict__ nd,
    const int* __restrict__ col_ptr, const int* __restrict__ csr_src,
    float* __restrict__ hout, int N) {
  int wid = (blockIdx.x * 256 + threadIdx.x) >> 6;
  int lane = threadIdx.x & 63;
  if (wid >= N) return;
  int v = wid;
  int p0 = col_ptr[v], p1 = col_ptr[v + 1];
  float s2v = s2pb[v];
  float ndv = nd[v];
  float ax = 0.f, ay = 0.f;
  for (int base = p0; base < p1; base += 64) {
    int idx = base + lane;
    int u = 0;
    float cf = 0.f;
    if (idx < p1) {
      u = csr_src[idx];
      cf = tanhf(s1[u] + s2v) * nd[u] * ndv;
    }
    int cnt = p1 - base;
    if (cnt > 64) cnt = 64;
    int j = 0;
    for (; j + 4 <= cnt; j += 4) {
      int u0 = __shfl(u, j + 0), u1 = __shfl(u, j + 1);
      int u2 = __shfl(u, j + 2), u3 = __shfl(u, j + 3);
      float c0 = __shfl(cf, j + 0), c1 = __shfl(cf, j + 1);
      float c2 = __shfl(cf, j + 2), c3 = __shfl(cf, j + 3);
      float2 h0 = *(const float2*)&h[(size_t)u0 * H_DIM + lane * 2];
      float2 h1 = *(const float2*)&h[(size_t)u1 * H_DIM + lane * 2];
      float2 h2 = *(const float2*)&h[(size_t)u2 * H_DIM + lane * 2];
      float2 h3 = *(const float2*)&h[(size_t)u3 * H_DIM + lane * 2];
      ax += c0 * h0.x + c1 * h1.x + c2 * h2.x + c3 * h3.x;
      ay += c0 * h0.y + c1 * h1.y + c2 * h2.y + c3 * h3.y;
    }
    for (; j < cnt; ++j) {
      int uj = __shfl(u, j);
      float cj = __shfl(cf, j);
      float2 hv = *(const float2*)&h[(size_t)uj * H_DIM + lane * 2];
      ax += cj * hv.x;
      ay += cj * hv.y;
    }
  }
  float2 rv = *(const float2*)&raw[(size_t)v * H_DIM + lane * 2];
  float2 o;
  o.x = EPS_F * rv.x + ax;
  o.y = EPS_F * rv.y + ay;
  *(float2*)&hout[(size_t)v * H_DIM + lane * 2] = o;
}

// ---------------- GEMM2 + log_softmax ----------------

__global__ __launch_bounds__(256) void gemm2_lsm(const float* __restrict__ h,
    const float* __restrict__ w, const float* __restrict__ b,
    float* __restrict__ out, int N) {
  __shared__ float ws[C_DIM][129];
  __shared__ float bsh[C_DIM];
  __shared__ float hsm[4][H_DIM];
  int t = threadIdx.x;
  for (int i = t; i < C_DIM * H_DIM; i += 256) ws[i / H_DIM][i % H_DIM] = w[i];
  if (t < C_DIM) bsh[t] = b[t];
  __syncthreads();
  int wave = t >> 6, lane = t & 63;
  for (int vb = blockIdx.x * 4; vb < N; vb += gridDim.x * 4) {
    int v = vb + wave;
    bool act = v < N;
    if (act) {
      float2 hv = *(const float2*)&h[(size_t)v * H_DIM + lane * 2];
      hsm[wave][lane * 2] = hv.x;
      hsm[wave][lane * 2 + 1] = hv.y;
    }
    __syncthreads();
    float acc = 0.f;
    if (act && lane < C_DIM) {
#pragma unroll 8
      for (int k = 0; k < H_DIM; ++k)
        acc = fmaf(hsm[wave][k], ws[lane][k], acc);
      acc += bsh[lane];
    }
    float m = (lane < C_DIM) ? acc : -1e30f;
    for (int off = 32; off > 0; off >>= 1) m = fmaxf(m, __shfl_xor(m, off));
    float ex = (lane < C_DIM) ? expf(acc - m) : 0.f;
    float s = ex;
    for (int off = 32; off > 0; off >>= 1) s += __shfl_xor(s, off);
    float lse = m + logf(s);
    if (act && lane < C_DIM) out[(size_t)v * C_DIM + lane] = acc - lse;
    __syncthreads();
  }
}

// ---------------- launch ----------------

extern "C" void kernel_launch(void* const* d_in, const int* in_sizes, int n_in,
                              void* d_out, int out_size, void* d_ws, size_t ws_size,
                              hipStream_t stream) {
  const float* x   = (const float*)d_in[0];
  const float* t1w = (const float*)d_in[1];
  const float* t1b = (const float*)d_in[2];
  const float* t2w = (const float*)d_in[3];
  const float* t2b = (const float*)d_in[4];
  const float* gw  = (const float*)d_in[5];
  const float* gb  = (const float*)d_in[6];
  const int*   ei  = (const int*)d_in[7];
  const int N = in_sizes[0] / F_DIM;
  const int E = in_sizes[7] / 2;
  float* out = (float*)d_out;

  char* p = (char*)d_ws;
  auto take = [&](size_t bytes) {
    char* r = p;
    p += (bytes + 255) & ~(size_t)255;
    return r;
  };
  float* h0 = (float*)take((size_t)N * H_DIM * 4);
  float* h1 = (float*)take((size_t)N * H_DIM * 4);
  float* h2 = (float*)take((size_t)N * H_DIM * 4);
  float* s1 = (float*)take((size_t)N * 4);
  float* s2 = (float*)take((size_t)N * 4);
  float* nd = (float*)take((size_t)N * 4);
  int* col_ptr = (int*)take((size_t)(N + 1) * 4);
  int* csr_src = (int*)take((size_t)E * 4);

  const int nbkt = (N + 255) >> 8;              // 196
  const int chunk = (E + NBLK - 1) / NBLK;      // 5000
  const int M = 2 * nbkt * NBLK;                // 62720
  const int scanblocks = (M + 255) / 256;       // 245 (<=256)

  int* blkhist = (int*)take((size_t)M * 4);
  int* sc      = (int*)take((size_t)M * 4);
  int* part    = (int*)take(256 * 4);
  u64* colpart = (u64*)take((size_t)E * 8);
  int* rowpart = (int*)take((size_t)E * 4);

  const int* row = ei;
  const int* col = ei + E;

  part_count<<<NBLK, 256, 0, stream>>>(row, col, blkhist, E, nbkt, chunk);
  scan_partial<<<scanblocks, 256, 0, stream>>>(blkhist, part, M);
  scan_single<<<1, 256, 0, stream>>>(part, scanblocks);
  scan_apply<<<scanblocks, 256, 0, stream>>>(blkhist, part, sc, M);
  part_scatter<<<NBLK, 256, 0, stream>>>(row, col, sc, colpart, rowpart, E, nbkt, chunk);
  bucket_csr<<<nbkt, 256, 0, stream>>>(colpart, sc, col_ptr, csr_src, N, E, nbkt);
  bucket_deg<<<nbkt, 256, 0, stream>>>(rowpart, sc, nd, N, E, nbkt);

  gemm1_mfma<<<(N + 63) / 64, 256, 0, stream>>>(x, t1w, t1b, h0, N);

  int nwb = (N + 3) / 4;
  gate_s<<<nwb, 256, 0, stream>>>(h0, gw + 0 * 2 * H_DIM, gb, 0, s1, s2, N);
  agg_kernel<<<nwb, 256, 0, stream>>>(h0, h0, s1, s2, nd, col_ptr, csr_src, h1, N);
  gate_s<<<nwb, 256, 0, stream>>>(h1, gw + 1 * 2 * H_DIM, gb, 1, s1, s2, N);
  agg_kernel<<<nwb, 256, 0, stream>>>(h1, h0, s1, s2, nd, col_ptr, csr_src, h2, N);

  gemm2_lsm<<<1024, 256, 0, stream>>>(h2, t2w, t2b, out, N);
}

// Round 4
// 218.448 us; speedup vs baseline: 1.9288x; 1.2141x over previous
//
#include <hip/hip_runtime.h>
#include <math.h>

#define F_DIM 512
#define H_DIM 128
#define C_DIM 40
#define EPS_F 0.3f
#define NBLK 160   // partition blocks (keeps scan <= 256 blocks for nbkt<=204)

typedef float f32x4 __attribute__((ext_vector_type(4)));
typedef unsigned int u32x4 __attribute__((ext_vector_type(4)));
typedef __bf16 bf16x8 __attribute__((ext_vector_type(8)));
typedef unsigned long long u64;
typedef unsigned short ushort_t;

__device__ inline float bflo(unsigned t) { return __builtin_bit_cast(float, t << 16); }
__device__ inline float bfhi(unsigned t) { return __builtin_bit_cast(float, t & 0xffff0000u); }
__device__ inline unsigned short f2bf(float f) {
  unsigned u = __builtin_bit_cast(unsigned, f);
  u = (u + 0x7fffu + ((u >> 16) & 1u)) >> 16;
  return (unsigned short)u;
}
__device__ inline unsigned pack2bf(float a, float b) {
  unsigned ua = __builtin_bit_cast(unsigned, a);
  unsigned ub = __builtin_bit_cast(unsigned, b);
  ua = (ua + 0x7fffu + ((ua >> 16) & 1u)) >> 16;
  ub = (ub + 0x7fffu + ((ub >> 16) & 1u)) >> 16;
  return ua | (ub << 16);
}

// ---------------- CSR build, no global atomics ----------------

__global__ __launch_bounds__(256) void part_count(const int* __restrict__ row,
    const int* __restrict__ col, int* __restrict__ blkhist, int E, int nbkt, int chunk) {
  __shared__ int ch[256], rh[256];
  int t = threadIdx.x, b = blockIdx.x;
  ch[t] = 0; rh[t] = 0;
  __syncthreads();
  int s = b * chunk, e = min(E, s + chunk);
  for (int i = s + t; i < e; i += 256) {
    atomicAdd(&ch[((unsigned)col[i]) >> 8], 1);
    atomicAdd(&rh[((unsigned)row[i]) >> 8], 1);
  }
  __syncthreads();
  if (t < nbkt) {
    blkhist[t * NBLK + b] = ch[t];
    blkhist[nbkt * NBLK + t * NBLK + b] = rh[t];
  }
}

__global__ __launch_bounds__(256) void scan_partial(const int* __restrict__ cnt,
    int* __restrict__ part, int M) {
  __shared__ int sd[256];
  int t = threadIdx.x;
  int i = blockIdx.x * 256 + t;
  sd[t] = (i < M) ? cnt[i] : 0;
  __syncthreads();
  for (int s = 128; s > 0; s >>= 1) {
    if (t < s) sd[t] += sd[t + s];
    __syncthreads();
  }
  if (t == 0) part[blockIdx.x] = sd[0];
}

__global__ __launch_bounds__(256) void scan_single(int* __restrict__ part, int P) {
  __shared__ int sd[256];
  int t = threadIdx.x;
  sd[t] = (t < P) ? part[t] : 0;
  __syncthreads();
  for (int off = 1; off < 256; off <<= 1) {
    int add = (t >= off) ? sd[t - off] : 0;
    __syncthreads();
    sd[t] += add;
    __syncthreads();
  }
  if (t < P) part[t] = (t == 0) ? 0 : sd[t - 1];
}

__global__ __launch_bounds__(256) void scan_apply(const int* __restrict__ cnt,
    const int* __restrict__ part, int* __restrict__ sc, int M) {
  __shared__ int sd[256];
  int t = threadIdx.x;
  int i = blockIdx.x * 256 + t;
  int v = (i < M) ? cnt[i] : 0;
  sd[t] = v;
  __syncthreads();
  for (int off = 1; off < 256; off <<= 1) {
    int add = (t >= off) ? sd[t - off] : 0;
    __syncthreads();
    sd[t] += add;
    __syncthreads();
  }
  if (i < M) {
    int excl = (t == 0) ? 0 : sd[t - 1];
    sc[i] = part[blockIdx.x] + excl;
  }
}

__global__ __launch_bounds__(256) void part_scatter(const int* __restrict__ row,
    const int* __restrict__ col, const int* __restrict__ sc,
    u64* __restrict__ colpart, int* __restrict__ rowpart, int E, int nbkt, int chunk) {
  __shared__ int cbase[256], rbase[256], coff[256], roff[256];
  int t = threadIdx.x, b = blockIdx.x;
  if (t < nbkt) {
    cbase[t] = sc[t * NBLK + b];
    rbase[t] = sc[nbkt * NBLK + t * NBLK + b] - E;
  }
  coff[t] = 0; roff[t] = 0;
  __syncthreads();
  int s = b * chunk, e = min(E, s + chunk);
  for (int i = s + t; i < e; i += 256) {
    unsigned c = (unsigned)col[i], r = (unsigned)row[i];
    int pc = cbase[c >> 8] + atomicAdd(&coff[c >> 8], 1);
    colpart[pc] = ((u64)r << 32) | (u64)c;
    int pr = rbase[r >> 8] + atomicAdd(&roff[r >> 8], 1);
    rowpart[pr] = (int)r;
  }
}

__global__ __launch_bounds__(256) void bucket_csr(const u64* __restrict__ colpart,
    const int* __restrict__ sc, int* __restrict__ col_ptr, int* __restrict__ csr_src,
    int N, int E, int nbkt) {
  __shared__ int cnt[256], ex[256], off[256];
  int t = threadIdx.x, bkt = blockIdx.x;
  int s = sc[bkt * NBLK];
  int e = sc[(bkt + 1) * NBLK];
  cnt[t] = 0; off[t] = 0;
  __syncthreads();
  for (int i = s + t; i < e; i += 256)
    atomicAdd(&cnt[(int)(colpart[i] & 255u)], 1);
  __syncthreads();
  ex[t] = cnt[t];
  __syncthreads();
  for (int o = 1; o < 256; o <<= 1) {
    int v = (t >= o) ? ex[t - o] : 0;
    __syncthreads();
    ex[t] += v;
    __syncthreads();
  }
  int excl = (t == 0) ? 0 : ex[t - 1];
  __syncthreads();
  ex[t] = excl;
  __syncthreads();
  int node = bkt * 256 + t;
  if (node < N) col_ptr[node] = s + ex[t];
  if (bkt == 0 && t == 0) col_ptr[N] = E;
  for (int i = s + t; i < e; i += 256) {
    u64 p = colpart[i];
    int lb = (int)(p & 255u);
    int dst = s + ex[lb] + atomicAdd(&off[lb], 1);
    csr_src[dst] = (int)(p >> 32);
  }
}

__global__ __launch_bounds__(256) void bucket_deg(const int* __restrict__ rowpart,
    const int* __restrict__ sc, float* __restrict__ nd, int N, int E, int nbkt) {
  __shared__ int cnt[256];
  int t = threadIdx.x, bkt = blockIdx.x;
  int s = sc[nbkt * NBLK + bkt * NBLK] - E;
  int e = (bkt < nbkt - 1) ? (sc[nbkt * NBLK + (bkt + 1) * NBLK] - E) : E;
  cnt[t] = 0;
  __syncthreads();
  for (int i = s + t; i < e; i += 256)
    atomicAdd(&cnt[rowpart[i] & 255], 1);
  __syncthreads();
  int node = bkt * 256 + t;
  if (node < N) {
    int d = cnt[t] < 1 ? 1 : cnt[t];
    nd[node] = 1.0f / sqrtf((float)d);
  }
}

// ---------------- GEMM1 (bf16 MFMA): h0 = relu(x @ t1_w.T + b), bf16 out ----------------

__global__ __launch_bounds__(256) void gemm1_mfma(const float* __restrict__ x,
    const float* __restrict__ w, const float* __restrict__ b,
    ushort_t* __restrict__ hbf, int N) {
  __shared__ u32x4 AsBuf[512];
  __shared__ u32x4 BsBuf[1024];
  char* Asc = (char*)AsBuf;
  char* Bsc = (char*)BsBuf;

  int t = threadIdx.x;
  int lane = t & 63;
  int wid = t >> 6;
  int wm = wid >> 1;
  int wn = wid & 1;
  int m0 = blockIdx.x * 64;

  f32x4 acc[2][4];
#pragma unroll
  for (int i = 0; i < 2; ++i)
#pragma unroll
    for (int j = 0; j < 4; ++j) acc[i][j] = (f32x4){0.f, 0.f, 0.f, 0.f};

  float bias[4];
#pragma unroll
  for (int j = 0; j < 4; ++j) bias[j] = b[wn * 64 + j * 16 + (lane & 15)];

  for (int kk = 0; kk < F_DIM; kk += 64) {
#pragma unroll
    for (int q = 0; q < 2; ++q) {
      int c = q * 256 + t;
      int row = c >> 3, kc = c & 7;
      int gm = m0 + row;
      f32x4 v0 = {0.f, 0.f, 0.f, 0.f}, v1 = {0.f, 0.f, 0.f, 0.f};
      if (gm < N) {
        const float* src = &x[(size_t)gm * F_DIM + kk + kc * 8];
        v0 = *(const f32x4*)src;
        v1 = *(const f32x4*)(src + 4);
      }
      u32x4 pk;
      pk[0] = pack2bf(v0[0], v0[1]);
      pk[1] = pack2bf(v0[2], v0[3]);
      pk[2] = pack2bf(v1[0], v1[1]);
      pk[3] = pack2bf(v1[2], v1[3]);
      *(u32x4*)(Asc + row * 128 + ((kc ^ (row & 7)) << 4)) = pk;
    }
#pragma unroll
    for (int q = 0; q < 4; ++q) {
      int c = q * 256 + t;
      int row = c >> 3, kc = c & 7;
      const float* src = &w[(size_t)row * F_DIM + kk + kc * 8];
      f32x4 v0 = *(const f32x4*)src;
      f32x4 v1 = *(const f32x4*)(src + 4);
      u32x4 pk;
      pk[0] = pack2bf(v0[0], v0[1]);
      pk[1] = pack2bf(v0[2], v0[3]);
      pk[2] = pack2bf(v1[0], v1[1]);
      pk[3] = pack2bf(v1[2], v1[3]);
      *(u32x4*)(Bsc + row * 128 + ((kc ^ (row & 7)) << 4)) = pk;
    }
    __syncthreads();
#pragma unroll
    for (int kh = 0; kh < 2; ++kh) {
      bf16x8 af[2], bfr[4];
      int kc = kh * 4 + (lane >> 4);
#pragma unroll
      for (int i = 0; i < 2; ++i) {
        int row = wm * 32 + i * 16 + (lane & 15);
        af[i] = *(const bf16x8*)(Asc + row * 128 + ((kc ^ (row & 7)) << 4));
      }
#pragma unroll
      for (int j = 0; j < 4; ++j) {
        int row = wn * 64 + j * 16 + (lane & 15);
        bfr[j] = *(const bf16x8*)(Bsc + row * 128 + ((kc ^ (row & 7)) << 4));
      }
#pragma unroll
      for (int i = 0; i < 2; ++i)
#pragma unroll
        for (int j = 0; j < 4; ++j)
          acc[i][j] = __builtin_amdgcn_mfma_f32_16x16x32_bf16(af[i], bfr[j], acc[i][j], 0, 0, 0);
    }
    __syncthreads();
  }

#pragma unroll
  for (int i = 0; i < 2; ++i)
#pragma unroll
    for (int j = 0; j < 4; ++j) {
      int col = wn * 64 + j * 16 + (lane & 15);
      int rbase = m0 + wm * 32 + i * 16 + ((lane >> 4) * 4);
#pragma unroll
      for (int r = 0; r < 4; ++r) {
        int gr = rbase + r;
        if (gr < N) hbf[(size_t)gr * H_DIM + col] = f2bf(fmaxf(acc[i][j][r] + bias[j], 0.f));
      }
    }
}

// ---------------- per-node gate scalars (bf16 h) ----------------

__global__ __launch_bounds__(256) void gate_s(const ushort_t* __restrict__ hbf,
    const float* __restrict__ gwl, const float* __restrict__ gb, int layer,
    float* __restrict__ s1, float* __restrict__ s2, int N) {
  int wid = (blockIdx.x * 256 + threadIdx.x) >> 6;
  int lane = threadIdx.x & 63;
  if (wid >= N) return;
  unsigned tv = *(const unsigned*)&hbf[(size_t)wid * H_DIM + lane * 2];
  float hx = bflo(tv), hy = bfhi(tv);
  float2 g1 = *(const float2*)&gwl[lane * 2];
  float2 g2 = *(const float2*)&gwl[H_DIM + lane * 2];
  float p1 = hx * g1.x + hy * g1.y;
  float p2 = hx * g2.x + hy * g2.y;
  for (int off = 32; off > 0; off >>= 1) {
    p1 += __shfl_xor(p1, off);
    p2 += __shfl_xor(p2, off);
  }
  if (lane == 0) {
    s1[wid] = p1;
    s2[wid] = p2 + gb[layer];
  }
}

// ---------------- aggregation (bf16 gathers, f32 accumulate, bf16 out) ----------------

__global__ __launch_bounds__(256) void agg_kernel(const ushort_t* __restrict__ hbf,
    const ushort_t* __restrict__ rawbf, const float* __restrict__ s1,
    const float* __restrict__ s2pb, const float* __restrict__ nd,
    const int* __restrict__ col_ptr, const int* __restrict__ csr_src,
    ushort_t* __restrict__ houtbf, int N) {
  int wid = (blockIdx.x * 256 + threadIdx.x) >> 6;
  int lane = threadIdx.x & 63;
  if (wid >= N) return;
  int v = wid;
  int p0 = col_ptr[v], p1 = col_ptr[v + 1];
  float s2v = s2pb[v];
  float ndv = nd[v];
  float ax = 0.f, ay = 0.f;
  for (int base = p0; base < p1; base += 64) {
    int idx = base + lane;
    int u = 0;
    float cf = 0.f;
    if (idx < p1) {
      u = csr_src[idx];
      cf = tanhf(s1[u] + s2v) * nd[u] * ndv;
    }
    int cnt = p1 - base;
    if (cnt > 64) cnt = 64;
    int j = 0;
    for (; j + 4 <= cnt; j += 4) {
      int u0 = __shfl(u, j + 0), u1 = __shfl(u, j + 1);
      int u2 = __shfl(u, j + 2), u3 = __shfl(u, j + 3);
      float c0 = __shfl(cf, j + 0), c1 = __shfl(cf, j + 1);
      float c2 = __shfl(cf, j + 2), c3 = __shfl(cf, j + 3);
      unsigned t0 = *(const unsigned*)&hbf[(size_t)u0 * H_DIM + lane * 2];
      unsigned t1 = *(const unsigned*)&hbf[(size_t)u1 * H_DIM + lane * 2];
      unsigned t2 = *(const unsigned*)&hbf[(size_t)u2 * H_DIM + lane * 2];
      unsigned t3 = *(const unsigned*)&hbf[(size_t)u3 * H_DIM + lane * 2];
      ax += c0 * bflo(t0) + c1 * bflo(t1) + c2 * bflo(t2) + c3 * bflo(t3);
      ay += c0 * bfhi(t0) + c1 * bfhi(t1) + c2 * bfhi(t2) + c3 * bfhi(t3);
    }
    for (; j < cnt; ++j) {
      int uj = __shfl(u, j);
      float cj = __shfl(cf, j);
      unsigned tj = *(const unsigned*)&hbf[(size_t)uj * H_DIM + lane * 2];
      ax += cj * bflo(tj);
      ay += cj * bfhi(tj);
    }
  }
  unsigned rv = *(const unsigned*)&rawbf[(size_t)v * H_DIM + lane * 2];
  float ox = EPS_F * bflo(rv) + ax;
  float oy = EPS_F * bfhi(rv) + ay;
  *(unsigned*)&houtbf[(size_t)v * H_DIM + lane * 2] = pack2bf(ox, oy);
}

// ---------------- GEMM2 + log_softmax (bf16 h in) ----------------

__global__ __launch_bounds__(256) void gemm2_lsm(const ushort_t* __restrict__ hbf,
    const float* __restrict__ w, const float* __restrict__ b,
    float* __restrict__ out, int N) {
  __shared__ float ws[C_DIM][129];
  __shared__ float bsh[C_DIM];
  __shared__ float hsm[4][H_DIM];
  int t = threadIdx.x;
  for (int i = t; i < C_DIM * H_DIM; i += 256) ws[i / H_DIM][i % H_DIM] = w[i];
  if (t < C_DIM) bsh[t] = b[t];
  __syncthreads();
  int wave = t >> 6, lane = t & 63;
  for (int vb = blockIdx.x * 4; vb < N; vb += gridDim.x * 4) {
    int v = vb + wave;
    bool act = v < N;
    if (act) {
      unsigned hv = *(const unsigned*)&hbf[(size_t)v * H_DIM + lane * 2];
      hsm[wave][lane * 2] = bflo(hv);
      hsm[wave][lane * 2 + 1] = bfhi(hv);
    }
    __syncthreads();
    float acc = 0.f;
    if (act && lane < C_DIM) {
#pragma unroll 8
      for (int k = 0; k < H_DIM; ++k)
        acc = fmaf(hsm[wave][k], ws[lane][k], acc);
      acc += bsh[lane];
    }
    float m = (lane < C_DIM) ? acc : -1e30f;
    for (int off = 32; off > 0; off >>= 1) m = fmaxf(m, __shfl_xor(m, off));
    float ex = (lane < C_DIM) ? expf(acc - m) : 0.f;
    float s = ex;
    for (int off = 32; off > 0; off >>= 1) s += __shfl_xor(s, off);
    float lse = m + logf(s);
    if (act && lane < C_DIM) out[(size_t)v * C_DIM + lane] = acc - lse;
    __syncthreads();
  }
}

// ---------------- launch ----------------

extern "C" void kernel_launch(void* const* d_in, const int* in_sizes, int n_in,
                              void* d_out, int out_size, void* d_ws, size_t ws_size,
                              hipStream_t stream) {
  const float* x   = (const float*)d_in[0];
  const float* t1w = (const float*)d_in[1];
  const float* t1b = (const float*)d_in[2];
  const float* t2w = (const float*)d_in[3];
  const float* t2b = (const float*)d_in[4];
  const float* gw  = (const float*)d_in[5];
  const float* gb  = (const float*)d_in[6];
  const int*   ei  = (const int*)d_in[7];
  const int N = in_sizes[0] / F_DIM;
  const int E = in_sizes[7] / 2;
  float* out = (float*)d_out;

  char* p = (char*)d_ws;
  auto take = [&](size_t bytes) {
    char* r = p;
    p += (bytes + 255) & ~(size_t)255;
    return r;
  };
  ushort_t* h0 = (ushort_t*)take((size_t)N * H_DIM * 2);
  ushort_t* h1 = (ushort_t*)take((size_t)N * H_DIM * 2);
  ushort_t* h2 = (ushort_t*)take((size_t)N * H_DIM * 2);
  float* s1 = (float*)take((size_t)N * 4);
  float* s2 = (float*)take((size_t)N * 4);
  float* nd = (float*)take((size_t)N * 4);
  int* col_ptr = (int*)take((size_t)(N + 1) * 4);
  int* csr_src = (int*)take((size_t)E * 4);

  const int nbkt = (N + 255) >> 8;              // 196
  const int chunk = (E + NBLK - 1) / NBLK;      // 5000
  const int M = 2 * nbkt * NBLK;                // 62720
  const int scanblocks = (M + 255) / 256;       // 245 (<=256)

  int* blkhist = (int*)take((size_t)M * 4);
  int* sc      = (int*)take((size_t)M * 4);
  int* part    = (int*)take(256 * 4);
  u64* colpart = (u64*)take((size_t)E * 8);
  int* rowpart = (int*)take((size_t)E * 4);

  const int* row = ei;
  const int* col = ei + E;

  part_count<<<NBLK, 256, 0, stream>>>(row, col, blkhist, E, nbkt, chunk);
  scan_partial<<<scanblocks, 256, 0, stream>>>(blkhist, part, M);
  scan_single<<<1, 256, 0, stream>>>(part, scanblocks);
  scan_apply<<<scanblocks, 256, 0, stream>>>(blkhist, part, sc, M);
  part_scatter<<<NBLK, 256, 0, stream>>>(row, col, sc, colpart, rowpart, E, nbkt, chunk);
  bucket_csr<<<nbkt, 256, 0, stream>>>(colpart, sc, col_ptr, csr_src, N, E, nbkt);
  bucket_deg<<<nbkt, 256, 0, stream>>>(rowpart, sc, nd, N, E, nbkt);

  gemm1_mfma<<<(N + 63) / 64, 256, 0, stream>>>(x, t1w, t1b, h0, N);

  int nwb = (N + 3) / 4;
  gate_s<<<nwb, 256, 0, stream>>>(h0, gw + 0 * 2 * H_DIM, gb, 0, s1, s2, N);
  agg_kernel<<<nwb, 256, 0, stream>>>(h0, h0, s1, s2, nd, col_ptr, csr_src, h1, N);
  gate_s<<<nwb, 256, 0, stream>>>(h1, gw + 1 * 2 * H_DIM, gb, 1, s1, s2, N);
  agg_kernel<<<nwb, 256, 0, stream>>>(h1, h0, s1, s2, nd, col_ptr, csr_src, h2, N);

  gemm2_lsm<<<1024, 256, 0, stream>>>(h2, t2w, t2b, out, N);
}

// Round 5
// 210.753 us; speedup vs baseline: 1.9992x; 1.0365x over previous
//
#include <hip/hip_runtime.h>
#include <math.h>

#define F_DIM 512
#define H_DIM 128
#define C_DIM 40
#define EPS_F 0.3f
#define NBLK 256   // partition blocks

typedef float f32x4 __attribute__((ext_vector_type(4)));
typedef unsigned int u32x4 __attribute__((ext_vector_type(4)));
typedef __bf16 bf16x8 __attribute__((ext_vector_type(8)));
typedef unsigned short ushort_t;
typedef unsigned char uchar_t;

__device__ inline float bflo(unsigned t) { return __builtin_bit_cast(float, t << 16); }
__device__ inline float bfhi(unsigned t) { return __builtin_bit_cast(float, t & 0xffff0000u); }
__device__ inline unsigned short f2bf(float f) {
  unsigned u = __builtin_bit_cast(unsigned, f);
  u = (u + 0x7fffu + ((u >> 16) & 1u)) >> 16;
  return (unsigned short)u;
}
__device__ inline unsigned pack2bf(float a, float b) {
  unsigned ua = __builtin_bit_cast(unsigned, a);
  unsigned ub = __builtin_bit_cast(unsigned, b);
  ua = (ua + 0x7fffu + ((ua >> 16) & 1u)) >> 16;
  ub = (ub + 0x7fffu + ((ub >> 16) & 1u)) >> 16;
  return ua | (ub << 16);
}

// ---------------- CSR build: 3 kernels, LDS-scope atomics only ----------------
// Buckets: node>>8 (nbkt = ceil(N/256)). Requires N < 65536 (payload packing).

__global__ __launch_bounds__(256) void part_count(const int* __restrict__ row,
    const int* __restrict__ col, int* __restrict__ blkhist, int E, int nbkt, int chunk) {
  __shared__ int ch[256], rh[256];
  int t = threadIdx.x, b = blockIdx.x;
  ch[t] = 0; rh[t] = 0;
  __syncthreads();
  int s = b * chunk, e = min(E, s + chunk);
  for (int i = s + t; i < e; i += 256) {
    atomicAdd(&ch[((unsigned)col[i]) >> 8], 1);
    atomicAdd(&rh[((unsigned)row[i]) >> 8], 1);
  }
  __syncthreads();
  if (t < nbkt) {
    blkhist[t * NBLK + b] = ch[t];
    blkhist[(nbkt + t) * NBLK + b] = rh[t];
  }
}

// Self-contained scan + scatter: each block recomputes the global prefix
// structure from blkhist (L2-resident), then scatters its edge chunk.
__global__ __launch_bounds__(256) void part_scatter(const int* __restrict__ row,
    const int* __restrict__ col, const int* __restrict__ blkhist,
    int* __restrict__ bktbase, unsigned* __restrict__ colpart,
    uchar_t* __restrict__ rowpart, int E, int nbkt, int chunk) {
  __shared__ int sbase[400];   // in-row prefix up to this block
  __shared__ int stot[400];    // row totals
  __shared__ int psum[256];    // pair-scan workspace
  __shared__ int sc[400];      // final global base per bucket-row for this block
  __shared__ int coff[400];    // running offsets during scatter
  int t = threadIdx.x, b = blockIdx.x;
  int nrows = 2 * nbkt;        // 392
  for (int rr = t; rr < nrows; rr += 256) {
    const int* rp = &blkhist[rr * NBLK];
    int pre = 0, tot = 0;
    for (int i = 0; i < NBLK; ++i) {
      int v = rp[i];
      pre += (i < b) ? v : 0;
      tot += v;
    }
    sbase[rr] = pre; stot[rr] = tot;
  }
  __syncthreads();
  // exclusive scan of stot[0..nrows) via pair-compression (supports up to 512 rows)
  int e0 = (2 * t     < nrows) ? stot[2 * t]     : 0;
  int e1 = (2 * t + 1 < nrows) ? stot[2 * t + 1] : 0;
  psum[t] = e0 + e1;
  __syncthreads();
  for (int off = 1; off < 256; off <<= 1) {
    int add = (t >= off) ? psum[t - off] : 0;
    __syncthreads();
    psum[t] += add;
    __syncthreads();
  }
  int pex = (t == 0) ? 0 : psum[t - 1];
  if (2 * t < nrows)     sc[2 * t]     = pex + sbase[2 * t];
  if (2 * t + 1 < nrows) sc[2 * t + 1] = pex + e0 + sbase[2 * t + 1];
  if (b == 0) {
    if (2 * t < nrows)     bktbase[2 * t]     = pex;
    if (2 * t + 1 < nrows) bktbase[2 * t + 1] = pex + e0;
    if (t == 0) bktbase[nrows] = 2 * E;
  }
  for (int rr = t; rr < nrows; rr += 256) coff[rr] = 0;
  __syncthreads();
  int s = b * chunk, e = min(E, s + chunk);
  for (int i = s + t; i < e; i += 256) {
    unsigned c = (unsigned)col[i], r = (unsigned)row[i];
    int bc = (int)(c >> 8), br = (int)(r >> 8);
    int pc = sc[bc] + atomicAdd(&coff[bc], 1);
    colpart[pc] = (r << 8) | (c & 255u);       // N < 2^16: fits 24 bits
    int pr = sc[nbkt + br] + atomicAdd(&coff[nbkt + br], 1) - E;
    rowpart[pr] = (uchar_t)(r & 255u);
  }
}

// blocks [0,nbkt): counting-sort bucket -> col_ptr + csr_src
// blocks [nbkt,2*nbkt): degree histogram -> nd
__global__ __launch_bounds__(256) void bucket_both(const unsigned* __restrict__ colpart,
    const uchar_t* __restrict__ rowpart, const int* __restrict__ bktbase,
    int* __restrict__ col_ptr, int* __restrict__ csr_src, float* __restrict__ nd,
    int N, int E, int nbkt) {
  __shared__ int cnt[256], ex[256], off[256];
  int t = threadIdx.x, bb = blockIdx.x;
  if (bb < nbkt) {
    int bkt = bb;
    int s = bktbase[bkt], e = bktbase[bkt + 1];
    cnt[t] = 0; off[t] = 0;
    __syncthreads();
    for (int i = s + t; i < e; i += 256)
      atomicAdd(&cnt[(int)(colpart[i] & 255u)], 1);
    __syncthreads();
    ex[t] = cnt[t];
    __syncthreads();
    for (int o = 1; o < 256; o <<= 1) {
      int v = (t >= o) ? ex[t - o] : 0;
      __syncthreads();
      ex[t] += v;
      __syncthreads();
    }
    int excl = (t == 0) ? 0 : ex[t - 1];
    __syncthreads();
    ex[t] = excl;
    __syncthreads();
    int node = bkt * 256 + t;
    if (node < N) col_ptr[node] = s + ex[t];
    if (bkt == 0 && t == 0) col_ptr[N] = E;
    for (int i = s + t; i < e; i += 256) {
      unsigned p = colpart[i];
      int lb = (int)(p & 255u);
      int dst = s + ex[lb] + atomicAdd(&off[lb], 1);
      csr_src[dst] = (int)(p >> 8);
    }
  } else {
    int bkt = bb - nbkt;
    int s = bktbase[nbkt + bkt] - E, e = bktbase[nbkt + bkt + 1] - E;
    cnt[t] = 0;
    __syncthreads();
    for (int i = s + t; i < e; i += 256)
      atomicAdd(&cnt[(int)rowpart[i]], 1);
    __syncthreads();
    int node = bkt * 256 + t;
    if (node < N) {
      int d = cnt[t] < 1 ? 1 : cnt[t];
      nd[node] = 1.0f / sqrtf((float)d);
    }
  }
}

// ---------------- GEMM1 (bf16 MFMA): h0 = relu(x @ t1_w.T + b), bf16 out ----------------
// BM=128, BN=128, BK=64. 4 waves as 2x2, each wave 64x64 (M_rep=4, N_rep=4).

__global__ __launch_bounds__(256) void gemm1_mfma(const float* __restrict__ x,
    const float* __restrict__ w, const float* __restrict__ b,
    ushort_t* __restrict__ hbf, int N) {
  __shared__ u32x4 AsBuf[1024];   // 128 rows * 128 B
  __shared__ u32x4 BsBuf[1024];   // 128 rows * 128 B
  char* Asc = (char*)AsBuf;
  char* Bsc = (char*)BsBuf;

  int t = threadIdx.x;
  int lane = t & 63;
  int wid = t >> 6;
  int wm = wid >> 1;
  int wn = wid & 1;
  int m0 = blockIdx.x * 128;

  f32x4 acc[4][4];
#pragma unroll
  for (int i = 0; i < 4; ++i)
#pragma unroll
    for (int j = 0; j < 4; ++j) acc[i][j] = (f32x4){0.f, 0.f, 0.f, 0.f};

  float bias[4];
#pragma unroll
  for (int j = 0; j < 4; ++j) bias[j] = b[wn * 64 + j * 16 + (lane & 15)];

  for (int kk = 0; kk < F_DIM; kk += 64) {
#pragma unroll
    for (int q = 0; q < 4; ++q) {
      int c = q * 256 + t;
      int row = c >> 3, kc = c & 7;
      int gm = m0 + row;
      f32x4 v0 = {0.f, 0.f, 0.f, 0.f}, v1 = {0.f, 0.f, 0.f, 0.f};
      if (gm < N) {
        const float* src = &x[(size_t)gm * F_DIM + kk + kc * 8];
        v0 = *(const f32x4*)src;
        v1 = *(const f32x4*)(src + 4);
      }
      u32x4 pk;
      pk[0] = pack2bf(v0[0], v0[1]);
      pk[1] = pack2bf(v0[2], v0[3]);
      pk[2] = pack2bf(v1[0], v1[1]);
      pk[3] = pack2bf(v1[2], v1[3]);
      *(u32x4*)(Asc + row * 128 + ((kc ^ (row & 7)) << 4)) = pk;
    }
#pragma unroll
    for (int q = 0; q < 4; ++q) {
      int c = q * 256 + t;
      int row = c >> 3, kc = c & 7;
      const float* src = &w[(size_t)row * F_DIM + kk + kc * 8];
      f32x4 v0 = *(const f32x4*)src;
      f32x4 v1 = *(const f32x4*)(src + 4);
      u32x4 pk;
      pk[0] = pack2bf(v0[0], v0[1]);
      pk[1] = pack2bf(v0[2], v0[3]);
      pk[2] = pack2bf(v1[0], v1[1]);
      pk[3] = pack2bf(v1[2], v1[3]);
      *(u32x4*)(Bsc + row * 128 + ((kc ^ (row & 7)) << 4)) = pk;
    }
    __syncthreads();
#pragma unroll
    for (int kh = 0; kh < 2; ++kh) {
      bf16x8 af[4], bfr[4];
      int kc = kh * 4 + (lane >> 4);
#pragma unroll
      for (int i = 0; i < 4; ++i) {
        int row = wm * 64 + i * 16 + (lane & 15);
        af[i] = *(const bf16x8*)(Asc + row * 128 + ((kc ^ (row & 7)) << 4));
      }
#pragma unroll
      for (int j = 0; j < 4; ++j) {
        int row = wn * 64 + j * 16 + (lane & 15);
        bfr[j] = *(const bf16x8*)(Bsc + row * 128 + ((kc ^ (row & 7)) << 4));
      }
#pragma unroll
      for (int i = 0; i < 4; ++i)
#pragma unroll
        for (int j = 0; j < 4; ++j)
          acc[i][j] = __builtin_amdgcn_mfma_f32_16x16x32_bf16(af[i], bfr[j], acc[i][j], 0, 0, 0);
    }
    __syncthreads();
  }

#pragma unroll
  for (int i = 0; i < 4; ++i)
#pragma unroll
    for (int j = 0; j < 4; ++j) {
      int col = wn * 64 + j * 16 + (lane & 15);
      int rbase = m0 + wm * 64 + i * 16 + ((lane >> 4) * 4);
#pragma unroll
      for (int r = 0; r < 4; ++r) {
        int gr = rbase + r;
        if (gr < N) hbf[(size_t)gr * H_DIM + col] = f2bf(fmaxf(acc[i][j][r] + bias[j], 0.f));
      }
    }
}

// ---------------- per-node gate scalars (layer 0 only; layer 1 fused into agg) ----------------

__global__ __launch_bounds__(256) void gate_s(const ushort_t* __restrict__ hbf,
    const float* __restrict__ gwl, const float* __restrict__ gb, int layer,
    float* __restrict__ s1, float* __restrict__ s2, int N) {
  int wid = (blockIdx.x * 256 + threadIdx.x) >> 6;
  int lane = threadIdx.x & 63;
  if (wid >= N) return;
  unsigned tv = *(const unsigned*)&hbf[(size_t)wid * H_DIM + lane * 2];
  float hx = bflo(tv), hy = bfhi(tv);
  float2 g1 = *(const float2*)&gwl[lane * 2];
  float2 g2 = *(const float2*)&gwl[H_DIM + lane * 2];
  float p1 = hx * g1.x + hy * g1.y;
  float p2 = hx * g2.x + hy * g2.y;
  for (int off = 32; off > 0; off >>= 1) {
    p1 += __shfl_xor(p1, off);
    p2 += __shfl_xor(p2, off);
  }
  if (lane == 0) {
    s1[wid] = p1;
    s2[wid] = p2 + gb[layer];
  }
}

// ---------------- aggregation (bf16 gathers, f32 accumulate, bf16 out, opt. fused gate) ----------------

template <bool GATE>
__global__ __launch_bounds__(256) void agg_kernel(const ushort_t* __restrict__ hbf,
    const ushort_t* __restrict__ rawbf, const float* __restrict__ s1,
    const float* __restrict__ s2pb, const float* __restrict__ nd,
    const int* __restrict__ col_ptr, const int* __restrict__ csr_src,
    ushort_t* __restrict__ houtbf,
    const float* __restrict__ gwl, const float* __restrict__ gb, int layer,
    float* __restrict__ s1o, float* __restrict__ s2o, int N) {
  int wid = (blockIdx.x * 256 + threadIdx.x) >> 6;
  int lane = threadIdx.x & 63;
  if (wid >= N) return;
  int v = wid;
  int p0 = col_ptr[v], p1 = col_ptr[v + 1];
  float s2v = s2pb[v];
  float ndv = nd[v];
  float ax = 0.f, ay = 0.f;
  for (int base = p0; base < p1; base += 64) {
    int idx = base + lane;
    int u = 0;
    float cf = 0.f;
    if (idx < p1) {
      u = csr_src[idx];
      cf = tanhf(s1[u] + s2v) * nd[u] * ndv;
    }
    int cnt = p1 - base;
    if (cnt > 64) cnt = 64;
    int j = 0;
    for (; j + 4 <= cnt; j += 4) {
      int u0 = __shfl(u, j + 0), u1 = __shfl(u, j + 1);
      int u2 = __shfl(u, j + 2), u3 = __shfl(u, j + 3);
      float c0 = __shfl(cf, j + 0), c1 = __shfl(cf, j + 1);
      float c2 = __shfl(cf, j + 2), c3 = __shfl(cf, j + 3);
      unsigned t0 = *(const unsigned*)&hbf[(size_t)u0 * H_DIM + lane * 2];
      unsigned t1 = *(const unsigned*)&hbf[(size_t)u1 * H_DIM + lane * 2];
      unsigned t2 = *(const unsigned*)&hbf[(size_t)u2 * H_DIM + lane * 2];
      unsigned t3 = *(const unsigned*)&hbf[(size_t)u3 * H_DIM + lane * 2];
      ax += c0 * bflo(t0) + c1 * bflo(t1) + c2 * bflo(t2) + c3 * bflo(t3);
      ay += c0 * bfhi(t0) + c1 * bfhi(t1) + c2 * bfhi(t2) + c3 * bfhi(t3);
    }
    for (; j < cnt; ++j) {
      int uj = __shfl(u, j);
      float cj = __shfl(cf, j);
      unsigned tj = *(const unsigned*)&hbf[(size_t)uj * H_DIM + lane * 2];
      ax += cj * bflo(tj);
      ay += cj * bfhi(tj);
    }
  }
  unsigned rv = *(const unsigned*)&rawbf[(size_t)v * H_DIM + lane * 2];
  float ox = EPS_F * bflo(rv) + ax;
  float oy = EPS_F * bfhi(rv) + ay;
  *(unsigned*)&houtbf[(size_t)v * H_DIM + lane * 2] = pack2bf(ox, oy);
  if (GATE) {
    float2 g1 = *(const float2*)&gwl[lane * 2];
    float2 g2 = *(const float2*)&gwl[H_DIM + lane * 2];
    float q1 = ox * g1.x + oy * g1.y;
    float q2 = ox * g2.x + oy * g2.y;
    for (int off = 32; off > 0; off >>= 1) {
      q1 += __shfl_xor(q1, off);
      q2 += __shfl_xor(q2, off);
    }
    if (lane == 0) {
      s1o[v] = q1;
      s2o[v] = q2 + gb[layer];
    }
  }
}

// ---------------- GEMM2 + log_softmax (bf16 h in) ----------------

__global__ __launch_bounds__(256) void gemm2_lsm(const ushort_t* __restrict__ hbf,
    const float* __restrict__ w, const float* __restrict__ b,
    float* __restrict__ out, int N) {
  __shared__ float ws[C_DIM][129];
  __shared__ float bsh[C_DIM];
  __shared__ float hsm[4][H_DIM];
  int t = threadIdx.x;
  for (int i = t; i < C_DIM * H_DIM; i += 256) ws[i / H_DIM][i % H_DIM] = w[i];
  if (t < C_DIM) bsh[t] = b[t];
  __syncthreads();
  int wave = t >> 6, lane = t & 63;
  for (int vb = blockIdx.x * 4; vb < N; vb += gridDim.x * 4) {
    int v = vb + wave;
    bool act = v < N;
    if (act) {
      unsigned hv = *(const unsigned*)&hbf[(size_t)v * H_DIM + lane * 2];
      hsm[wave][lane * 2] = bflo(hv);
      hsm[wave][lane * 2 + 1] = bfhi(hv);
    }
    __syncthreads();
    float acc = 0.f;
    if (act && lane < C_DIM) {
#pragma unroll 8
      for (int k = 0; k < H_DIM; ++k)
        acc = fmaf(hsm[wave][k], ws[lane][k], acc);
      acc += bsh[lane];
    }
    float m = (lane < C_DIM) ? acc : -1e30f;
    for (int off = 32; off > 0; off >>= 1) m = fmaxf(m, __shfl_xor(m, off));
    float ex = (lane < C_DIM) ? expf(acc - m) : 0.f;
    float s = ex;
    for (int off = 32; off > 0; off >>= 1) s += __shfl_xor(s, off);
    float lse = m + logf(s);
    if (act && lane < C_DIM) out[(size_t)v * C_DIM + lane] = acc - lse;
    __syncthreads();
  }
}

// ---------------- launch ----------------

extern "C" void kernel_launch(void* const* d_in, const int* in_sizes, int n_in,
                              void* d_out, int out_size, void* d_ws, size_t ws_size,
                              hipStream_t stream) {
  const float* x   = (const float*)d_in[0];
  const float* t1w = (const float*)d_in[1];
  const float* t1b = (const float*)d_in[2];
  const float* t2w = (const float*)d_in[3];
  const float* t2b = (const float*)d_in[4];
  const float* gw  = (const float*)d_in[5];
  const float* gb  = (const float*)d_in[6];
  const int*   ei  = (const int*)d_in[7];
  const int N = in_sizes[0] / F_DIM;
  const int E = in_sizes[7] / 2;
  float* out = (float*)d_out;

  char* p = (char*)d_ws;
  auto take = [&](size_t bytes) {
    char* r = p;
    p += (bytes + 255) & ~(size_t)255;
    return r;
  };
  ushort_t* h0 = (ushort_t*)take((size_t)N * H_DIM * 2);
  ushort_t* h1 = (ushort_t*)take((size_t)N * H_DIM * 2);
  ushort_t* h2 = (ushort_t*)take((size_t)N * H_DIM * 2);
  float* s1a = (float*)take((size_t)N * 4);
  float* s2a = (float*)take((size_t)N * 4);
  float* s1b = (float*)take((size_t)N * 4);
  float* s2b = (float*)take((size_t)N * 4);
  float* nd  = (float*)take((size_t)N * 4);
  int* col_ptr = (int*)take((size_t)(N + 1) * 4);
  int* csr_src = (int*)take((size_t)E * 4);

  const int nbkt = (N + 255) >> 8;              // 196
  const int chunk = (E + NBLK - 1) / NBLK;      // 3125

  int* blkhist = (int*)take((size_t)2 * nbkt * NBLK * 4);
  int* bktbase = (int*)take((size_t)(2 * nbkt + 1) * 4);
  unsigned* colpart = (unsigned*)take((size_t)E * 4);
  uchar_t* rowpart  = (uchar_t*)take((size_t)E);

  const int* row = ei;
  const int* col = ei + E;

  gemm1_mfma<<<(N + 127) / 128, 256, 0, stream>>>(x, t1w, t1b, h0, N);

  part_count<<<NBLK, 256, 0, stream>>>(row, col, blkhist, E, nbkt, chunk);
  part_scatter<<<NBLK, 256, 0, stream>>>(row, col, blkhist, bktbase, colpart, rowpart, E, nbkt, chunk);
  bucket_both<<<2 * nbkt, 256, 0, stream>>>(colpart, rowpart, bktbase, col_ptr, csr_src, nd, N, E, nbkt);

  int nwb = (N + 3) / 4;
  gate_s<<<nwb, 256, 0, stream>>>(h0, gw + 0 * 2 * H_DIM, gb, 0, s1a, s2a, N);
  agg_kernel<true><<<nwb, 256, 0, stream>>>(h0, h0, s1a, s2a, nd, col_ptr, csr_src, h1,
                                            gw + 1 * 2 * H_DIM, gb, 1, s1b, s2b, N);
  agg_kernel<false><<<nwb, 256, 0, stream>>>(h1, h0, s1b, s2b, nd, col_ptr, csr_src, h2,
                                             nullptr, nullptr, 0, nullptr, nullptr, N);

  gemm2_lsm<<<1024, 256, 0, stream>>>(h2, t2w, t2b, out, N);
}

// Round 6
// 192.646 us; speedup vs baseline: 2.1871x; 1.0940x over previous
//
#include <hip/hip_runtime.h>
#include <math.h>

#define F_DIM 512
#define H_DIM 128
#define C_DIM 40
#define EPS_F 0.3f
#define NBLK 256   // partition blocks

typedef float f32x4 __attribute__((ext_vector_type(4)));
typedef unsigned int u32x4 __attribute__((ext_vector_type(4)));
typedef __bf16 bf16x8 __attribute__((ext_vector_type(8)));
typedef unsigned short ushort_t;
typedef unsigned char uchar_t;

__device__ inline float bflo(unsigned t) { return __builtin_bit_cast(float, t << 16); }
__device__ inline float bfhi(unsigned t) { return __builtin_bit_cast(float, t & 0xffff0000u); }
__device__ inline unsigned short f2bf(float f) {
  unsigned u = __builtin_bit_cast(unsigned, f);
  u = (u + 0x7fffu + ((u >> 16) & 1u)) >> 16;
  return (unsigned short)u;
}
__device__ inline unsigned pack2bf(float a, float b) {
  unsigned ua = __builtin_bit_cast(unsigned, a);
  unsigned ub = __builtin_bit_cast(unsigned, b);
  ua = (ua + 0x7fffu + ((ua >> 16) & 1u)) >> 16;
  ub = (ub + 0x7fffu + ((ub >> 16) & 1u)) >> 16;
  return ua | (ub << 16);
}

// ---------------- CSR build: 3 kernels, LDS-scope atomics only ----------------

__global__ __launch_bounds__(256) void part_count(const int* __restrict__ row,
    const int* __restrict__ col, int* __restrict__ blkhist, int E, int nbkt, int chunk) {
  __shared__ int ch[256], rh[256];
  int t = threadIdx.x, b = blockIdx.x;
  ch[t] = 0; rh[t] = 0;
  __syncthreads();
  int s = b * chunk, e = min(E, s + chunk);
  for (int i = s + t; i < e; i += 256) {
    atomicAdd(&ch[((unsigned)col[i]) >> 8], 1);
    atomicAdd(&rh[((unsigned)row[i]) >> 8], 1);
  }
  __syncthreads();
  if (t < nbkt) {
    blkhist[t * NBLK + b] = ch[t];
    blkhist[(nbkt + t) * NBLK + b] = rh[t];
  }
}

__global__ __launch_bounds__(256) void part_scatter(const int* __restrict__ row,
    const int* __restrict__ col, const int* __restrict__ blkhist,
    int* __restrict__ bktbase, unsigned* __restrict__ colpart,
    uchar_t* __restrict__ rowpart, int E, int nbkt, int chunk) {
  __shared__ int sbase[400];
  __shared__ int stot[400];
  __shared__ int psum[256];
  __shared__ int sc[400];
  __shared__ int coff[400];
  int t = threadIdx.x, b = blockIdx.x;
  int nrows = 2 * nbkt;
  for (int rr = t; rr < nrows; rr += 256) {
    const int* rp = &blkhist[rr * NBLK];
    int pre = 0, tot = 0;
    for (int i = 0; i < NBLK; ++i) {
      int v = rp[i];
      pre += (i < b) ? v : 0;
      tot += v;
    }
    sbase[rr] = pre; stot[rr] = tot;
  }
  __syncthreads();
  int e0 = (2 * t     < nrows) ? stot[2 * t]     : 0;
  int e1 = (2 * t + 1 < nrows) ? stot[2 * t + 1] : 0;
  psum[t] = e0 + e1;
  __syncthreads();
  for (int off = 1; off < 256; off <<= 1) {
    int add = (t >= off) ? psum[t - off] : 0;
    __syncthreads();
    psum[t] += add;
    __syncthreads();
  }
  int pex = (t == 0) ? 0 : psum[t - 1];
  if (2 * t < nrows)     sc[2 * t]     = pex + sbase[2 * t];
  if (2 * t + 1 < nrows) sc[2 * t + 1] = pex + e0 + sbase[2 * t + 1];
  if (b == 0) {
    if (2 * t < nrows)     bktbase[2 * t]     = pex;
    if (2 * t + 1 < nrows) bktbase[2 * t + 1] = pex + e0;
    if (t == 0) bktbase[nrows] = 2 * E;
  }
  for (int rr = t; rr < nrows; rr += 256) coff[rr] = 0;
  __syncthreads();
  int s = b * chunk, e = min(E, s + chunk);
  for (int i = s + t; i < e; i += 256) {
    unsigned c = (unsigned)col[i], r = (unsigned)row[i];
    int bc = (int)(c >> 8), br = (int)(r >> 8);
    int pc = sc[bc] + atomicAdd(&coff[bc], 1);
    colpart[pc] = (r << 8) | (c & 255u);
    int pr = sc[nbkt + br] + atomicAdd(&coff[nbkt + br], 1) - E;
    rowpart[pr] = (uchar_t)(r & 255u);
  }
}

__global__ __launch_bounds__(256) void bucket_both(const unsigned* __restrict__ colpart,
    const uchar_t* __restrict__ rowpart, const int* __restrict__ bktbase,
    int* __restrict__ col_ptr, int* __restrict__ csr_src, float* __restrict__ nd,
    int N, int E, int nbkt) {
  __shared__ int cnt[256], ex[256], off[256];
  int t = threadIdx.x, bb = blockIdx.x;
  if (bb < nbkt) {
    int bkt = bb;
    int s = bktbase[bkt], e = bktbase[bkt + 1];
    cnt[t] = 0; off[t] = 0;
    __syncthreads();
    for (int i = s + t; i < e; i += 256)
      atomicAdd(&cnt[(int)(colpart[i] & 255u)], 1);
    __syncthreads();
    ex[t] = cnt[t];
    __syncthreads();
    for (int o = 1; o < 256; o <<= 1) {
      int v = (t >= o) ? ex[t - o] : 0;
      __syncthreads();
      ex[t] += v;
      __syncthreads();
    }
    int excl = (t == 0) ? 0 : ex[t - 1];
    __syncthreads();
    ex[t] = excl;
    __syncthreads();
    int node = bkt * 256 + t;
    if (node < N) col_ptr[node] = s + ex[t];
    if (bkt == 0 && t == 0) col_ptr[N] = E;
    for (int i = s + t; i < e; i += 256) {
      unsigned p = colpart[i];
      int lb = (int)(p & 255u);
      int dst = s + ex[lb] + atomicAdd(&off[lb], 1);
      csr_src[dst] = (int)(p >> 8);
    }
  } else {
    int bkt = bb - nbkt;
    int s = bktbase[nbkt + bkt] - E, e = bktbase[nbkt + bkt + 1] - E;
    cnt[t] = 0;
    __syncthreads();
    for (int i = s + t; i < e; i += 256)
      atomicAdd(&cnt[(int)rowpart[i]], 1);
    __syncthreads();
    int node = bkt * 256 + t;
    if (node < N) {
      int d = cnt[t] < 1 ? 1 : cnt[t];
      nd[node] = 1.0f / sqrtf((float)d);
    }
  }
}

// ---------------- GEMM1 (bf16 MFMA) + fused gate0 ----------------
// BM=128, BN=128, BK=64. 4 waves as 2x2, each wave 64x64.
// Epilogue also computes s1 = h.g1, s2 = h.g2 + gb[0], packs (s1, nd) per node.

__global__ __launch_bounds__(256) void gemm1_mfma(const float* __restrict__ x,
    const float* __restrict__ w, const float* __restrict__ b,
    const float* __restrict__ gwl, const float* __restrict__ gb,
    const float* __restrict__ nd,
    ushort_t* __restrict__ hbf, float2* __restrict__ pack0,
    float* __restrict__ s2a, int N) {
  __shared__ u32x4 AsBuf[1024];
  __shared__ u32x4 BsBuf[1024];
  char* Asc = (char*)AsBuf;
  char* Bsc = (char*)BsBuf;

  int t = threadIdx.x;
  int lane = t & 63;
  int wid = t >> 6;
  int wm = wid >> 1;
  int wn = wid & 1;
  int m0 = blockIdx.x * 128;
  int ql = lane & 15;

  f32x4 acc[4][4];
#pragma unroll
  for (int i = 0; i < 4; ++i)
#pragma unroll
    for (int j = 0; j < 4; ++j) acc[i][j] = (f32x4){0.f, 0.f, 0.f, 0.f};

  float bias[4], g1v[4], g2v[4];
#pragma unroll
  for (int j = 0; j < 4; ++j) {
    int c = wn * 64 + j * 16 + ql;
    bias[j] = b[c];
    g1v[j] = gwl[c];
    g2v[j] = gwl[H_DIM + c];
  }

  for (int kk = 0; kk < F_DIM; kk += 64) {
#pragma unroll
    for (int q = 0; q < 4; ++q) {
      int c = q * 256 + t;
      int row = c >> 3, kc = c & 7;
      int gm = m0 + row;
      f32x4 v0 = {0.f, 0.f, 0.f, 0.f}, v1 = {0.f, 0.f, 0.f, 0.f};
      if (gm < N) {
        const float* src = &x[(size_t)gm * F_DIM + kk + kc * 8];
        v0 = *(const f32x4*)src;
        v1 = *(const f32x4*)(src + 4);
      }
      u32x4 pk;
      pk[0] = pack2bf(v0[0], v0[1]);
      pk[1] = pack2bf(v0[2], v0[3]);
      pk[2] = pack2bf(v1[0], v1[1]);
      pk[3] = pack2bf(v1[2], v1[3]);
      *(u32x4*)(Asc + row * 128 + ((kc ^ (row & 7)) << 4)) = pk;
    }
#pragma unroll
    for (int q = 0; q < 4; ++q) {
      int c = q * 256 + t;
      int row = c >> 3, kc = c & 7;
      const float* src = &w[(size_t)row * F_DIM + kk + kc * 8];
      f32x4 v0 = *(const f32x4*)src;
      f32x4 v1 = *(const f32x4*)(src + 4);
      u32x4 pk;
      pk[0] = pack2bf(v0[0], v0[1]);
      pk[1] = pack2bf(v0[2], v0[3]);
      pk[2] = pack2bf(v1[0], v1[1]);
      pk[3] = pack2bf(v1[2], v1[3]);
      *(u32x4*)(Bsc + row * 128 + ((kc ^ (row & 7)) << 4)) = pk;
    }
    __syncthreads();
#pragma unroll
    for (int kh = 0; kh < 2; ++kh) {
      bf16x8 af[4], bfr[4];
      int kc = kh * 4 + (lane >> 4);
#pragma unroll
      for (int i = 0; i < 4; ++i) {
        int row = wm * 64 + i * 16 + ql;
        af[i] = *(const bf16x8*)(Asc + row * 128 + ((kc ^ (row & 7)) << 4));
      }
#pragma unroll
      for (int j = 0; j < 4; ++j) {
        int row = wn * 64 + j * 16 + ql;
        bfr[j] = *(const bf16x8*)(Bsc + row * 128 + ((kc ^ (row & 7)) << 4));
      }
#pragma unroll
      for (int i = 0; i < 4; ++i)
#pragma unroll
        for (int j = 0; j < 4; ++j)
          acc[i][j] = __builtin_amdgcn_mfma_f32_16x16x32_bf16(af[i], bfr[j], acc[i][j], 0, 0, 0);
    }
    __syncthreads();
  }

  // epilogue: write h0 (bf16) + accumulate gate partials
  float gp1[4][4], gp2[4][4];   // [i][r]
#pragma unroll
  for (int i = 0; i < 4; ++i)
#pragma unroll
    for (int r = 0; r < 4; ++r) { gp1[i][r] = 0.f; gp2[i][r] = 0.f; }

#pragma unroll
  for (int i = 0; i < 4; ++i) {
    int rbase = m0 + wm * 64 + i * 16 + ((lane >> 4) * 4);
#pragma unroll
    for (int j = 0; j < 4; ++j) {
      int col = wn * 64 + j * 16 + ql;
#pragma unroll
      for (int r = 0; r < 4; ++r) {
        int gr = rbase + r;
        float o = fmaxf(acc[i][j][r] + bias[j], 0.f);
        if (gr < N) hbf[(size_t)gr * H_DIM + col] = f2bf(o);
        gp1[i][r] = fmaf(o, g1v[j], gp1[i][r]);
        gp2[i][r] = fmaf(o, g2v[j], gp2[i][r]);
      }
    }
  }
  // reduce over the 16 lanes that share a row (low 4 lane bits)
#pragma unroll
  for (int i = 0; i < 4; ++i)
#pragma unroll
    for (int r = 0; r < 4; ++r) {
#pragma unroll
      for (int m = 1; m < 16; m <<= 1) {
        gp1[i][r] += __shfl_xor(gp1[i][r], m);
        gp2[i][r] += __shfl_xor(gp2[i][r], m);
      }
    }
  // cross-wave combine via LDS overlay on (now dead) AsBuf
  float* pgA = (float*)AsBuf;          // [128][2]
  float* pgB = (float*)AsBuf + 256;    // [128][2]
  if (ql == 0) {
#pragma unroll
    for (int i = 0; i < 4; ++i)
#pragma unroll
      for (int r = 0; r < 4; ++r) {
        int lr = wm * 64 + i * 16 + (lane >> 4) * 4 + r;
        pgA[lr * 2 + wn] = gp1[i][r];
        pgB[lr * 2 + wn] = gp2[i][r];
      }
  }
  __syncthreads();
  if (t < 128) {
    int gr = m0 + t;
    if (gr < N) {
      float p1 = pgA[t * 2] + pgA[t * 2 + 1];
      float p2 = pgB[t * 2] + pgB[t * 2 + 1];
      float ndv = nd[gr];
      pack0[gr] = make_float2(p1, ndv);
      s2a[gr] = p2 + gb[0];
    }
  }
}

// ---------------- aggregation: 16-lane x 16B gathers, 4 edges per wave-step ----------------
// MODE 1: h1 = EPS*raw + agg(h0); fused gate1 -> pack1, s2b
// MODE 2: h2 = EPS*raw + agg(h1); fused gemm2 + log_softmax -> out

template <int MODE>
__global__ __launch_bounds__(256) void agg_kernel(const ushort_t* __restrict__ hbf,
    const ushort_t* __restrict__ rawbf, const float2* __restrict__ pack,
    const float* __restrict__ s2pb, const float* __restrict__ nd,
    const int* __restrict__ col_ptr, const int* __restrict__ csr_src,
    ushort_t* __restrict__ houtbf,
    const float* __restrict__ gwl, const float* __restrict__ gb,
    float2* __restrict__ packo, float* __restrict__ s2o,
    const float* __restrict__ w2, const float* __restrict__ b2,
    float* __restrict__ out, int N) {
  __shared__ float ws[(MODE == 2 ? C_DIM : 1)][129];
  __shared__ float bsh[(MODE == 2 ? C_DIM : 1)];
  __shared__ float hsm[(MODE == 2 ? 4 : 1)][H_DIM];
  int t = threadIdx.x;
  int wave = t >> 6, lane = t & 63;
  int g = lane >> 4, q = lane & 15;
  if (MODE == 2) {
    for (int i = t; i < C_DIM * H_DIM; i += 256) ws[i / H_DIM][i % H_DIM] = w2[i];
    if (t < C_DIM) bsh[t] = b2[t];
    __syncthreads();
  }
  int v = blockIdx.x * 4 + wave;
  bool act = v < N;

  float acc8[8];
#pragma unroll
  for (int k = 0; k < 8; ++k) acc8[k] = 0.f;
  float o[8];
  float ndv = 0.f;

  if (act) {
    int p0 = col_ptr[v], p1 = col_ptr[v + 1];
    float s2v = s2pb[v];
    ndv = nd[v];
    for (int base = p0; base < p1; base += 64) {
      int idx = base + lane;
      int u = 0;
      float cf = 0.f;
      if (idx < p1) {
        u = csr_src[idx];
        float2 pk = pack[u];
        cf = tanhf(pk.x + s2v) * pk.y * ndv;
      }
      int cnt = p1 - base;
      if (cnt > 64) cnt = 64;
      for (int j = 0; j < cnt; j += 4) {
        int e = j + g;
        int ue = __shfl(u, e);
        float ce = __shfl(cf, e);
        u32x4 hv = *(const u32x4*)&hbf[(size_t)ue * H_DIM + q * 8];
        acc8[0] = fmaf(ce, bflo(hv[0]), acc8[0]);
        acc8[1] = fmaf(ce, bfhi(hv[0]), acc8[1]);
        acc8[2] = fmaf(ce, bflo(hv[1]), acc8[2]);
        acc8[3] = fmaf(ce, bfhi(hv[1]), acc8[3]);
        acc8[4] = fmaf(ce, bflo(hv[2]), acc8[4]);
        acc8[5] = fmaf(ce, bfhi(hv[2]), acc8[5]);
        acc8[6] = fmaf(ce, bflo(hv[3]), acc8[6]);
        acc8[7] = fmaf(ce, bfhi(hv[3]), acc8[7]);
      }
    }
    // sum the 4 lane-groups (same q, different g)
#pragma unroll
    for (int k = 0; k < 8; ++k) {
      acc8[k] += __shfl_xor(acc8[k], 16);
      acc8[k] += __shfl_xor(acc8[k], 32);
    }
    u32x4 rv = *(const u32x4*)&rawbf[(size_t)v * H_DIM + q * 8];
    o[0] = fmaf(EPS_F, bflo(rv[0]), acc8[0]);
    o[1] = fmaf(EPS_F, bfhi(rv[0]), acc8[1]);
    o[2] = fmaf(EPS_F, bflo(rv[1]), acc8[2]);
    o[3] = fmaf(EPS_F, bfhi(rv[1]), acc8[3]);
    o[4] = fmaf(EPS_F, bflo(rv[2]), acc8[4]);
    o[5] = fmaf(EPS_F, bfhi(rv[2]), acc8[5]);
    o[6] = fmaf(EPS_F, bflo(rv[3]), acc8[6]);
    o[7] = fmaf(EPS_F, bfhi(rv[3]), acc8[7]);

    if (MODE == 1) {
      if (g == 0) {
        u32x4 pk;
        pk[0] = pack2bf(o[0], o[1]);
        pk[1] = pack2bf(o[2], o[3]);
        pk[2] = pack2bf(o[4], o[5]);
        pk[3] = pack2bf(o[6], o[7]);
        *(u32x4*)&houtbf[(size_t)v * H_DIM + q * 8] = pk;
      }
      // fused gate: dot(h1_row, g1/g2); all 4 groups hold identical o -> reduce over q only
      f32x4 ga0 = *(const f32x4*)&gwl[q * 8];
      f32x4 ga1 = *(const f32x4*)&gwl[q * 8 + 4];
      f32x4 gb0 = *(const f32x4*)&gwl[H_DIM + q * 8];
      f32x4 gb1 = *(const f32x4*)&gwl[H_DIM + q * 8 + 4];
      float q1 = o[0] * ga0[0] + o[1] * ga0[1] + o[2] * ga0[2] + o[3] * ga0[3]
               + o[4] * ga1[0] + o[5] * ga1[1] + o[6] * ga1[2] + o[7] * ga1[3];
      float q2 = o[0] * gb0[0] + o[1] * gb0[1] + o[2] * gb0[2] + o[3] * gb0[3]
               + o[4] * gb1[0] + o[5] * gb1[1] + o[6] * gb1[2] + o[7] * gb1[3];
#pragma unroll
      for (int m = 1; m < 16; m <<= 1) {
        q1 += __shfl_xor(q1, m);
        q2 += __shfl_xor(q2, m);
      }
      if (lane == 0) {
        packo[v] = make_float2(q1, ndv);
        s2o[v] = q2 + gb[0];
      }
    }
  }

  if (MODE == 2) {
    if (act && g == 0) {
#pragma unroll
      for (int k = 0; k < 8; ++k) hsm[wave][q * 8 + k] = o[k];
    }
    __syncthreads();
    float accv = 0.f;
    if (act && lane < C_DIM) {
#pragma unroll 8
      for (int k = 0; k < H_DIM; ++k)
        accv = fmaf(hsm[wave][k], ws[lane][k], accv);
      accv += bsh[lane];
    }
    float m = (lane < C_DIM) ? accv : -1e30f;
    for (int off = 32; off > 0; off >>= 1) m = fmaxf(m, __shfl_xor(m, off));
    float ex = (lane < C_DIM) ? expf(accv - m) : 0.f;
    float s = ex;
    for (int off = 32; off > 0; off >>= 1) s += __shfl_xor(s, off);
    float lse = m + logf(s);
    if (act && lane < C_DIM) out[(size_t)v * C_DIM + lane] = accv - lse;
  }
}

// ---------------- launch ----------------

extern "C" void kernel_launch(void* const* d_in, const int* in_sizes, int n_in,
                              void* d_out, int out_size, void* d_ws, size_t ws_size,
                              hipStream_t stream) {
  const float* x   = (const float*)d_in[0];
  const float* t1w = (const float*)d_in[1];
  const float* t1b = (const float*)d_in[2];
  const float* t2w = (const float*)d_in[3];
  const float* t2b = (const float*)d_in[4];
  const float* gw  = (const float*)d_in[5];
  const float* gb  = (const float*)d_in[6];
  const int*   ei  = (const int*)d_in[7];
  const int N = in_sizes[0] / F_DIM;
  const int E = in_sizes[7] / 2;
  float* out = (float*)d_out;

  char* p = (char*)d_ws;
  auto take = [&](size_t bytes) {
    char* r = p;
    p += (bytes + 255) & ~(size_t)255;
    return r;
  };
  ushort_t* h0 = (ushort_t*)take((size_t)N * H_DIM * 2);
  ushort_t* h1 = (ushort_t*)take((size_t)N * H_DIM * 2);
  float2* pack0 = (float2*)take((size_t)N * 8);
  float2* pack1 = (float2*)take((size_t)N * 8);
  float* s2a = (float*)take((size_t)N * 4);
  float* s2b = (float*)take((size_t)N * 4);
  float* nd  = (float*)take((size_t)N * 4);
  int* col_ptr = (int*)take((size_t)(N + 1) * 4);
  int* csr_src = (int*)take((size_t)E * 4);

  const int nbkt = (N + 255) >> 8;              // 196
  const int chunk = (E + NBLK - 1) / NBLK;      // 3125

  int* blkhist = (int*)take((size_t)2 * nbkt * NBLK * 4);
  int* bktbase = (int*)take((size_t)(2 * nbkt + 1) * 4);
  unsigned* colpart = (unsigned*)take((size_t)E * 4);
  uchar_t* rowpart  = (uchar_t*)take((size_t)E);

  const int* row = ei;
  const int* col = ei + E;

  part_count<<<NBLK, 256, 0, stream>>>(row, col, blkhist, E, nbkt, chunk);
  part_scatter<<<NBLK, 256, 0, stream>>>(row, col, blkhist, bktbase, colpart, rowpart, E, nbkt, chunk);
  bucket_both<<<2 * nbkt, 256, 0, stream>>>(colpart, rowpart, bktbase, col_ptr, csr_src, nd, N, E, nbkt);

  gemm1_mfma<<<(N + 127) / 128, 256, 0, stream>>>(x, t1w, t1b, gw, gb, nd, h0, pack0, s2a, N);

  int nwb = (N + 3) / 4;
  agg_kernel<1><<<nwb, 256, 0, stream>>>(h0, h0, pack0, s2a, nd, col_ptr, csr_src, h1,
                                         gw + 2 * H_DIM, gb + 1, pack1, s2b,
                                         nullptr, nullptr, nullptr, N);
  agg_kernel<2><<<nwb, 256, 0, stream>>>(h1, h0, pack1, s2b, nd, col_ptr, csr_src, nullptr,
                                         nullptr, nullptr, nullptr, nullptr,
                                         t2w, t2b, out, N);
}

// Round 7
// 191.123 us; speedup vs baseline: 2.2045x; 1.0080x over previous
//
#include <hip/hip_runtime.h>
#include <math.h>

#define F_DIM 512
#define H_DIM 128
#define C_DIM 40
#define EPS_F 0.3f
#define NBLK 256   // partition blocks

typedef float f32x4 __attribute__((ext_vector_type(4)));
typedef unsigned int u32x4 __attribute__((ext_vector_type(4)));
typedef __bf16 bf16x8 __attribute__((ext_vector_type(8)));
typedef unsigned short ushort_t;
typedef unsigned char uchar_t;

__device__ inline float bflo(unsigned t) { return __builtin_bit_cast(float, t << 16); }
__device__ inline float bfhi(unsigned t) { return __builtin_bit_cast(float, t & 0xffff0000u); }
__device__ inline unsigned short f2bf(float f) {
  unsigned u = __builtin_bit_cast(unsigned, f);
  u = (u + 0x7fffu + ((u >> 16) & 1u)) >> 16;
  return (unsigned short)u;
}
__device__ inline unsigned pack2bf(float a, float b) {
  unsigned ua = __builtin_bit_cast(unsigned, a);
  unsigned ub = __builtin_bit_cast(unsigned, b);
  ua = (ua + 0x7fffu + ((ua >> 16) & 1u)) >> 16;
  ub = (ub + 0x7fffu + ((ub >> 16) & 1u)) >> 16;
  return ua | (ub << 16);
}

// ---------------- CSR build: 3 kernels, LDS-scope atomics only ----------------

__global__ __launch_bounds__(256) void part_count(const int* __restrict__ row,
    const int* __restrict__ col, int* __restrict__ blkhist, int E, int nbkt, int chunk) {
  __shared__ int ch[256], rh[256];
  int t = threadIdx.x, b = blockIdx.x;
  ch[t] = 0; rh[t] = 0;
  __syncthreads();
  int s = b * chunk, e = min(E, s + chunk);
  for (int i = s + t; i < e; i += 256) {
    atomicAdd(&ch[((unsigned)col[i]) >> 8], 1);
    atomicAdd(&rh[((unsigned)row[i]) >> 8], 1);
  }
  __syncthreads();
  if (t < nbkt) {
    blkhist[t * NBLK + b] = ch[t];
    blkhist[(nbkt + t) * NBLK + b] = rh[t];
  }
}

__global__ __launch_bounds__(256) void part_scatter(const int* __restrict__ row,
    const int* __restrict__ col, const int* __restrict__ blkhist,
    int* __restrict__ bktbase, unsigned* __restrict__ colpart,
    uchar_t* __restrict__ rowpart, int E, int nbkt, int chunk) {
  __shared__ int sbase[400];
  __shared__ int stot[400];
  __shared__ int psum[256];
  __shared__ int sc[400];
  __shared__ int coff[400];
  int t = threadIdx.x, b = blockIdx.x;
  int nrows = 2 * nbkt;
  for (int rr = t; rr < nrows; rr += 256) {
    const int* rp = &blkhist[rr * NBLK];
    int pre = 0, tot = 0;
    for (int i = 0; i < NBLK; ++i) {
      int v = rp[i];
      pre += (i < b) ? v : 0;
      tot += v;
    }
    sbase[rr] = pre; stot[rr] = tot;
  }
  __syncthreads();
  int e0 = (2 * t     < nrows) ? stot[2 * t]     : 0;
  int e1 = (2 * t + 1 < nrows) ? stot[2 * t + 1] : 0;
  psum[t] = e0 + e1;
  __syncthreads();
  for (int off = 1; off < 256; off <<= 1) {
    int add = (t >= off) ? psum[t - off] : 0;
    __syncthreads();
    psum[t] += add;
    __syncthreads();
  }
  int pex = (t == 0) ? 0 : psum[t - 1];
  if (2 * t < nrows)     sc[2 * t]     = pex + sbase[2 * t];
  if (2 * t + 1 < nrows) sc[2 * t + 1] = pex + e0 + sbase[2 * t + 1];
  if (b == 0) {
    if (2 * t < nrows)     bktbase[2 * t]     = pex;
    if (2 * t + 1 < nrows) bktbase[2 * t + 1] = pex + e0;
    if (t == 0) bktbase[nrows] = 2 * E;
  }
  for (int rr = t; rr < nrows; rr += 256) coff[rr] = 0;
  __syncthreads();
  int s = b * chunk, e = min(E, s + chunk);
  for (int i = s + t; i < e; i += 256) {
    unsigned c = (unsigned)col[i], r = (unsigned)row[i];
    int bc = (int)(c >> 8), br = (int)(r >> 8);
    int pc = sc[bc] + atomicAdd(&coff[bc], 1);
    colpart[pc] = (r << 8) | (c & 255u);
    int pr = sc[nbkt + br] + atomicAdd(&coff[nbkt + br], 1) - E;
    rowpart[pr] = (uchar_t)(r & 255u);
  }
}

__global__ __launch_bounds__(256) void bucket_both(const unsigned* __restrict__ colpart,
    const uchar_t* __restrict__ rowpart, const int* __restrict__ bktbase,
    int* __restrict__ col_ptr, int* __restrict__ csr_src, float* __restrict__ nd,
    int N, int E, int nbkt) {
  __shared__ int cnt[256], ex[256], off[256];
  int t = threadIdx.x, bb = blockIdx.x;
  if (bb < nbkt) {
    int bkt = bb;
    int s = bktbase[bkt], e = bktbase[bkt + 1];
    cnt[t] = 0; off[t] = 0;
    __syncthreads();
    for (int i = s + t; i < e; i += 256)
      atomicAdd(&cnt[(int)(colpart[i] & 255u)], 1);
    __syncthreads();
    ex[t] = cnt[t];
    __syncthreads();
    for (int o = 1; o < 256; o <<= 1) {
      int v = (t >= o) ? ex[t - o] : 0;
      __syncthreads();
      ex[t] += v;
      __syncthreads();
    }
    int excl = (t == 0) ? 0 : ex[t - 1];
    __syncthreads();
    ex[t] = excl;
    __syncthreads();
    int node = bkt * 256 + t;
    if (node < N) col_ptr[node] = s + ex[t];
    if (bkt == 0 && t == 0) col_ptr[N] = E;
    for (int i = s + t; i < e; i += 256) {
      unsigned p = colpart[i];
      int lb = (int)(p & 255u);
      int dst = s + ex[lb] + atomicAdd(&off[lb], 1);
      csr_src[dst] = (int)(p >> 8);
    }
  } else {
    int bkt = bb - nbkt;
    int s = bktbase[nbkt + bkt] - E, e = bktbase[nbkt + bkt + 1] - E;
    cnt[t] = 0;
    __syncthreads();
    for (int i = s + t; i < e; i += 256)
      atomicAdd(&cnt[(int)rowpart[i]], 1);
    __syncthreads();
    int node = bkt * 256 + t;
    if (node < N) {
      int d = cnt[t] < 1 ? 1 : cnt[t];
      nd[node] = 1.0f / sqrtf((float)d);
    }
  }
}

// ---------------- GEMM1 (bf16 MFMA) + fused gate0 ----------------

__global__ __launch_bounds__(256) void gemm1_mfma(const float* __restrict__ x,
    const float* __restrict__ w, const float* __restrict__ b,
    const float* __restrict__ gwl, const float* __restrict__ gb,
    const float* __restrict__ nd,
    ushort_t* __restrict__ hbf, float2* __restrict__ pack0,
    float* __restrict__ s2a, int N) {
  __shared__ u32x4 AsBuf[1024];
  __shared__ u32x4 BsBuf[1024];
  char* Asc = (char*)AsBuf;
  char* Bsc = (char*)BsBuf;

  int t = threadIdx.x;
  int lane = t & 63;
  int wid = t >> 6;
  int wm = wid >> 1;
  int wn = wid & 1;
  int m0 = blockIdx.x * 128;
  int ql = lane & 15;

  f32x4 acc[4][4];
#pragma unroll
  for (int i = 0; i < 4; ++i)
#pragma unroll
    for (int j = 0; j < 4; ++j) acc[i][j] = (f32x4){0.f, 0.f, 0.f, 0.f};

  float bias[4], g1v[4], g2v[4];
#pragma unroll
  for (int j = 0; j < 4; ++j) {
    int c = wn * 64 + j * 16 + ql;
    bias[j] = b[c];
    g1v[j] = gwl[c];
    g2v[j] = gwl[H_DIM + c];
  }

  for (int kk = 0; kk < F_DIM; kk += 64) {
#pragma unroll
    for (int q = 0; q < 4; ++q) {
      int c = q * 256 + t;
      int row = c >> 3, kc = c & 7;
      int gm = m0 + row;
      f32x4 v0 = {0.f, 0.f, 0.f, 0.f}, v1 = {0.f, 0.f, 0.f, 0.f};
      if (gm < N) {
        const float* src = &x[(size_t)gm * F_DIM + kk + kc * 8];
        v0 = *(const f32x4*)src;
        v1 = *(const f32x4*)(src + 4);
      }
      u32x4 pk;
      pk[0] = pack2bf(v0[0], v0[1]);
      pk[1] = pack2bf(v0[2], v0[3]);
      pk[2] = pack2bf(v1[0], v1[1]);
      pk[3] = pack2bf(v1[2], v1[3]);
      *(u32x4*)(Asc + row * 128 + ((kc ^ (row & 7)) << 4)) = pk;
    }
#pragma unroll
    for (int q = 0; q < 4; ++q) {
      int c = q * 256 + t;
      int row = c >> 3, kc = c & 7;
      const float* src = &w[(size_t)row * F_DIM + kk + kc * 8];
      f32x4 v0 = *(const f32x4*)src;
      f32x4 v1 = *(const f32x4*)(src + 4);
      u32x4 pk;
      pk[0] = pack2bf(v0[0], v0[1]);
      pk[1] = pack2bf(v0[2], v0[3]);
      pk[2] = pack2bf(v1[0], v1[1]);
      pk[3] = pack2bf(v1[2], v1[3]);
      *(u32x4*)(Bsc + row * 128 + ((kc ^ (row & 7)) << 4)) = pk;
    }
    __syncthreads();
#pragma unroll
    for (int kh = 0; kh < 2; ++kh) {
      bf16x8 af[4], bfr[4];
      int kc = kh * 4 + (lane >> 4);
#pragma unroll
      for (int i = 0; i < 4; ++i) {
        int row = wm * 64 + i * 16 + ql;
        af[i] = *(const bf16x8*)(Asc + row * 128 + ((kc ^ (row & 7)) << 4));
      }
#pragma unroll
      for (int j = 0; j < 4; ++j) {
        int row = wn * 64 + j * 16 + ql;
        bfr[j] = *(const bf16x8*)(Bsc + row * 128 + ((kc ^ (row & 7)) << 4));
      }
#pragma unroll
      for (int i = 0; i < 4; ++i)
#pragma unroll
        for (int j = 0; j < 4; ++j)
          acc[i][j] = __builtin_amdgcn_mfma_f32_16x16x32_bf16(af[i], bfr[j], acc[i][j], 0, 0, 0);
    }
    __syncthreads();
  }

  float gp1[4][4], gp2[4][4];
#pragma unroll
  for (int i = 0; i < 4; ++i)
#pragma unroll
    for (int r = 0; r < 4; ++r) { gp1[i][r] = 0.f; gp2[i][r] = 0.f; }

#pragma unroll
  for (int i = 0; i < 4; ++i) {
    int rbase = m0 + wm * 64 + i * 16 + ((lane >> 4) * 4);
#pragma unroll
    for (int j = 0; j < 4; ++j) {
      int col = wn * 64 + j * 16 + ql;
#pragma unroll
      for (int r = 0; r < 4; ++r) {
        int gr = rbase + r;
        float o = fmaxf(acc[i][j][r] + bias[j], 0.f);
        if (gr < N) hbf[(size_t)gr * H_DIM + col] = f2bf(o);
        gp1[i][r] = fmaf(o, g1v[j], gp1[i][r]);
        gp2[i][r] = fmaf(o, g2v[j], gp2[i][r]);
      }
    }
  }
#pragma unroll
  for (int i = 0; i < 4; ++i)
#pragma unroll
    for (int r = 0; r < 4; ++r) {
#pragma unroll
      for (int m = 1; m < 16; m <<= 1) {
        gp1[i][r] += __shfl_xor(gp1[i][r], m);
        gp2[i][r] += __shfl_xor(gp2[i][r], m);
      }
    }
  float* pgA = (float*)AsBuf;
  float* pgB = (float*)AsBuf + 256;
  if (ql == 0) {
#pragma unroll
    for (int i = 0; i < 4; ++i)
#pragma unroll
      for (int r = 0; r < 4; ++r) {
        int lr = wm * 64 + i * 16 + (lane >> 4) * 4 + r;
        pgA[lr * 2 + wn] = gp1[i][r];
        pgB[lr * 2 + wn] = gp2[i][r];
      }
  }
  __syncthreads();
  if (t < 128) {
    int gr = m0 + t;
    if (gr < N) {
      float p1 = pgA[t * 2] + pgA[t * 2 + 1];
      float p2 = pgB[t * 2] + pgB[t * 2 + 1];
      float ndv = nd[gr];
      pack0[gr] = make_float2(p1, ndv);
      s2a[gr] = p2 + gb[0];
    }
  }
}

// ---------------- aggregation: 16-lane x 16B gathers, 16-edge batches (MLP=4) ----------------
// MODE 1: h1 = EPS*raw + agg(h0); fused gate1 -> pack1, s2b
// MODE 2: h2 = EPS*raw + agg(h1); fused gemm2 + log_softmax -> out

template <int MODE>
__global__ __launch_bounds__(256) void agg_kernel(const ushort_t* __restrict__ hbf,
    const ushort_t* __restrict__ rawbf, const float2* __restrict__ pack,
    const float* __restrict__ s2pb, const float* __restrict__ nd,
    const int* __restrict__ col_ptr, const int* __restrict__ csr_src,
    ushort_t* __restrict__ houtbf,
    const float* __restrict__ gwl, const float* __restrict__ gb,
    float2* __restrict__ packo, float* __restrict__ s2o,
    const float* __restrict__ w2, const float* __restrict__ b2,
    float* __restrict__ out, int N) {
  // manual smem layout; MODE 1 uses ~0 LDS
  __shared__ float smem[(MODE == 2) ? (C_DIM * 129 + C_DIM + 4 * H_DIM) : 1];
  float* ws  = smem;                          // [C_DIM][129]
  float* bsh = smem + C_DIM * 129;            // [C_DIM]
  float* hsm = smem + C_DIM * 129 + C_DIM;    // [4][H_DIM]

  int t = threadIdx.x;
  int wave = t >> 6, lane = t & 63;
  int g = lane >> 4, q = lane & 15;
  if (MODE == 2) {
    for (int i = t; i < C_DIM * H_DIM; i += 256) ws[(i / H_DIM) * 129 + (i % H_DIM)] = w2[i];
    if (t < C_DIM) bsh[t] = b2[t];
    __syncthreads();
  }
  int v = blockIdx.x * 4 + wave;
  bool act = v < N;

  float acc8[8];
#pragma unroll
  for (int k = 0; k < 8; ++k) acc8[k] = 0.f;
  float o[8];
  float ndv = 0.f;

  if (act) {
    int p0 = col_ptr[v], p1v = col_ptr[v + 1];
    float s2v = s2pb[v];
    ndv = nd[v];
    // prefetch residual row early (independent of gathers)
    u32x4 rv = *(const u32x4*)&rawbf[(size_t)v * H_DIM + q * 8];
    const ushort_t* hq = hbf + q * 8;

    for (int base = p0; base < p1v; base += 64) {
      int idx = base + lane;
      int u = 0;
      float cf = 0.f;
      if (idx < p1v) {
        u = csr_src[idx];
        float2 pk = pack[u];
        cf = tanhf(pk.x + s2v) * pk.y * ndv;
      }
      int cnt = p1v - base;
      if (cnt > 64) cnt = 64;
      int j = 0;
      // 16-edge batches: 4 independent 16B gathers in flight per wave
      for (; j + 16 <= cnt; j += 16) {
        int e = j + g;
        int ue0 = __shfl(u, e);
        int ue1 = __shfl(u, e + 4);
        int ue2 = __shfl(u, e + 8);
        int ue3 = __shfl(u, e + 12);
        u32x4 h0 = *(const u32x4*)&hq[(size_t)ue0 * H_DIM];
        u32x4 h1 = *(const u32x4*)&hq[(size_t)ue1 * H_DIM];
        u32x4 h2 = *(const u32x4*)&hq[(size_t)ue2 * H_DIM];
        u32x4 h3 = *(const u32x4*)&hq[(size_t)ue3 * H_DIM];
        float ce0 = __shfl(cf, e);
        float ce1 = __shfl(cf, e + 4);
        float ce2 = __shfl(cf, e + 8);
        float ce3 = __shfl(cf, e + 12);
#pragma unroll
        for (int k = 0; k < 4; ++k) {
          acc8[2 * k]     = fmaf(ce0, bflo(h0[k]), acc8[2 * k]);
          acc8[2 * k + 1] = fmaf(ce0, bfhi(h0[k]), acc8[2 * k + 1]);
        }
#pragma unroll
        for (int k = 0; k < 4; ++k) {
          acc8[2 * k]     = fmaf(ce1, bflo(h1[k]), acc8[2 * k]);
          acc8[2 * k + 1] = fmaf(ce1, bfhi(h1[k]), acc8[2 * k + 1]);
        }
#pragma unroll
        for (int k = 0; k < 4; ++k) {
          acc8[2 * k]     = fmaf(ce2, bflo(h2[k]), acc8[2 * k]);
          acc8[2 * k + 1] = fmaf(ce2, bfhi(h2[k]), acc8[2 * k + 1]);
        }
#pragma unroll
        for (int k = 0; k < 4; ++k) {
          acc8[2 * k]     = fmaf(ce3, bflo(h3[k]), acc8[2 * k]);
          acc8[2 * k + 1] = fmaf(ce3, bfhi(h3[k]), acc8[2 * k + 1]);
        }
      }
      // tail: 4 edges per step
      for (; j < cnt; j += 4) {
        int e = j + g;
        int ue = __shfl(u, e);
        float ce = __shfl(cf, e);
        u32x4 hv = *(const u32x4*)&hq[(size_t)ue * H_DIM];
#pragma unroll
        for (int k = 0; k < 4; ++k) {
          acc8[2 * k]     = fmaf(ce, bflo(hv[k]), acc8[2 * k]);
          acc8[2 * k + 1] = fmaf(ce, bfhi(hv[k]), acc8[2 * k + 1]);
        }
      }
    }
    // sum the 4 lane-groups (same q, different g)
#pragma unroll
    for (int k = 0; k < 8; ++k) {
      acc8[k] += __shfl_xor(acc8[k], 16);
      acc8[k] += __shfl_xor(acc8[k], 32);
    }
    o[0] = fmaf(EPS_F, bflo(rv[0]), acc8[0]);
    o[1] = fmaf(EPS_F, bfhi(rv[0]), acc8[1]);
    o[2] = fmaf(EPS_F, bflo(rv[1]), acc8[2]);
    o[3] = fmaf(EPS_F, bfhi(rv[1]), acc8[3]);
    o[4] = fmaf(EPS_F, bflo(rv[2]), acc8[4]);
    o[5] = fmaf(EPS_F, bfhi(rv[2]), acc8[5]);
    o[6] = fmaf(EPS_F, bflo(rv[3]), acc8[6]);
    o[7] = fmaf(EPS_F, bfhi(rv[3]), acc8[7]);

    if (MODE == 1) {
      if (g == 0) {
        u32x4 pk;
        pk[0] = pack2bf(o[0], o[1]);
        pk[1] = pack2bf(o[2], o[3]);
        pk[2] = pack2bf(o[4], o[5]);
        pk[3] = pack2bf(o[6], o[7]);
        *(u32x4*)&houtbf[(size_t)v * H_DIM + q * 8] = pk;
      }
      f32x4 ga0 = *(const f32x4*)&gwl[q * 8];
      f32x4 ga1 = *(const f32x4*)&gwl[q * 8 + 4];
      f32x4 gb0 = *(const f32x4*)&gwl[H_DIM + q * 8];
      f32x4 gb1 = *(const f32x4*)&gwl[H_DIM + q * 8 + 4];
      float q1 = o[0] * ga0[0] + o[1] * ga0[1] + o[2] * ga0[2] + o[3] * ga0[3]
               + o[4] * ga1[0] + o[5] * ga1[1] + o[6] * ga1[2] + o[7] * ga1[3];
      float q2 = o[0] * gb0[0] + o[1] * gb0[1] + o[2] * gb0[2] + o[3] * gb0[3]
               + o[4] * gb1[0] + o[5] * gb1[1] + o[6] * gb1[2] + o[7] * gb1[3];
#pragma unroll
      for (int m = 1; m < 16; m <<= 1) {
        q1 += __shfl_xor(q1, m);
        q2 += __shfl_xor(q2, m);
      }
      if (lane == 0) {
        packo[v] = make_float2(q1, ndv);
        s2o[v] = q2 + gb[0];
      }
    }
  }

  if (MODE == 2) {
    if (act && g == 0) {
#pragma unroll
      for (int k = 0; k < 8; ++k) hsm[wave * H_DIM + q * 8 + k] = o[k];
    }
    __syncthreads();
    float accv = 0.f;
    if (act && lane < C_DIM) {
#pragma unroll 8
      for (int k = 0; k < H_DIM; ++k)
        accv = fmaf(hsm[wave * H_DIM + k], ws[lane * 129 + k], accv);
      accv += bsh[lane];
    }
    float m = (lane < C_DIM) ? accv : -1e30f;
    for (int off = 32; off > 0; off >>= 1) m = fmaxf(m, __shfl_xor(m, off));
    float ex = (lane < C_DIM) ? expf(accv - m) : 0.f;
    float s = ex;
    for (int off = 32; off > 0; off >>= 1) s += __shfl_xor(s, off);
    float lse = m + logf(s);
    if (act && lane < C_DIM) out[(size_t)v * C_DIM + lane] = accv - lse;
  }
}

// ---------------- launch ----------------

extern "C" void kernel_launch(void* const* d_in, const int* in_sizes, int n_in,
                              void* d_out, int out_size, void* d_ws, size_t ws_size,
                              hipStream_t stream) {
  const float* x   = (const float*)d_in[0];
  const float* t1w = (const float*)d_in[1];
  const float* t1b = (const float*)d_in[2];
  const float* t2w = (const float*)d_in[3];
  const float* t2b = (const float*)d_in[4];
  const float* gw  = (const float*)d_in[5];
  const float* gb  = (const float*)d_in[6];
  const int*   ei  = (const int*)d_in[7];
  const int N = in_sizes[0] / F_DIM;
  const int E = in_sizes[7] / 2;
  float* out = (float*)d_out;

  char* p = (char*)d_ws;
  auto take = [&](size_t bytes) {
    char* r = p;
    p += (bytes + 255) & ~(size_t)255;
    return r;
  };
  ushort_t* h0 = (ushort_t*)take((size_t)N * H_DIM * 2);
  ushort_t* h1 = (ushort_t*)take((size_t)N * H_DIM * 2);
  float2* pack0 = (float2*)take((size_t)N * 8);
  float2* pack1 = (float2*)take((size_t)N * 8);
  float* s2a = (float*)take((size_t)N * 4);
  float* s2b = (float*)take((size_t)N * 4);
  float* nd  = (float*)take((size_t)N * 4);
  int* col_ptr = (int*)take((size_t)(N + 1) * 4);
  int* csr_src = (int*)take((size_t)E * 4);

  const int nbkt = (N + 255) >> 8;              // 196
  const int chunk = (E + NBLK - 1) / NBLK;      // 3125

  int* blkhist = (int*)take((size_t)2 * nbkt * NBLK * 4);
  int* bktbase = (int*)take((size_t)(2 * nbkt + 1) * 4);
  unsigned* colpart = (unsigned*)take((size_t)E * 4);
  uchar_t* rowpart  = (uchar_t*)take((size_t)E);

  const int* row = ei;
  const int* col = ei + E;

  part_count<<<NBLK, 256, 0, stream>>>(row, col, blkhist, E, nbkt, chunk);
  part_scatter<<<NBLK, 256, 0, stream>>>(row, col, blkhist, bktbase, colpart, rowpart, E, nbkt, chunk);
  bucket_both<<<2 * nbkt, 256, 0, stream>>>(colpart, rowpart, bktbase, col_ptr, csr_src, nd, N, E, nbkt);

  gemm1_mfma<<<(N + 127) / 128, 256, 0, stream>>>(x, t1w, t1b, gw, gb, nd, h0, pack0, s2a, N);

  int nwb = (N + 3) / 4;
  agg_kernel<1><<<nwb, 256, 0, stream>>>(h0, h0, pack0, s2a, nd, col_ptr, csr_src, h1,
                                         gw + 2 * H_DIM, gb + 1, pack1, s2b,
                                         nullptr, nullptr, nullptr, N);
  agg_kernel<2><<<nwb, 256, 0, stream>>>(h1, h0, pack1, s2b, nd, col_ptr, csr_src, nullptr,
                                         nullptr, nullptr, nullptr, nullptr,
                                         t2w, t2b, out, N);
}

// Round 8
// 187.213 us; speedup vs baseline: 2.2506x; 1.0209x over previous
//
#include <hip/hip_runtime.h>
#include <math.h>

#define F_DIM 512
#define H_DIM 128
#define C_DIM 40
#define EPS_F 0.3f
#define NBLK 256   // partition blocks

typedef float f32x4 __attribute__((ext_vector_type(4)));
typedef unsigned int u32x4 __attribute__((ext_vector_type(4)));
typedef __bf16 bf16x8 __attribute__((ext_vector_type(8)));
typedef unsigned short ushort_t;
typedef unsigned char uchar_t;

__device__ inline float bflo(unsigned t) { return __builtin_bit_cast(float, t << 16); }
__device__ inline float bfhi(unsigned t) { return __builtin_bit_cast(float, t & 0xffff0000u); }
__device__ inline unsigned short f2bf(float f) {
  unsigned u = __builtin_bit_cast(unsigned, f);
  u = (u + 0x7fffu + ((u >> 16) & 1u)) >> 16;
  return (unsigned short)u;
}
__device__ inline unsigned pack2bf(float a, float b) {
  unsigned ua = __builtin_bit_cast(unsigned, a);
  unsigned ub = __builtin_bit_cast(unsigned, b);
  ua = (ua + 0x7fffu + ((ua >> 16) & 1u)) >> 16;
  ub = (ub + 0x7fffu + ((ub >> 16) & 1u)) >> 16;
  return ua | (ub << 16);
}
// fast tanh: 1 - 2/(e^{2x}+1); exact limits, ~1e-6 err
__device__ inline float fast_tanh(float x) {
  float e = __expf(2.0f * x);
  return 1.0f - 2.0f / (e + 1.0f);
}

// ---------------- CSR build: 3 kernels, LDS-scope atomics only ----------------

__global__ __launch_bounds__(256) void part_count(const int* __restrict__ row,
    const int* __restrict__ col, int* __restrict__ blkhist, int E, int nbkt, int chunk) {
  __shared__ int ch[256], rh[256];
  int t = threadIdx.x, b = blockIdx.x;
  ch[t] = 0; rh[t] = 0;
  __syncthreads();
  int s = b * chunk, e = min(E, s + chunk);
  for (int i = s + t; i < e; i += 256) {
    atomicAdd(&ch[((unsigned)col[i]) >> 8], 1);
    atomicAdd(&rh[((unsigned)row[i]) >> 8], 1);
  }
  __syncthreads();
  if (t < nbkt) {
    blkhist[t * NBLK + b] = ch[t];
    blkhist[(nbkt + t) * NBLK + b] = rh[t];
  }
}

__global__ __launch_bounds__(256) void part_scatter(const int* __restrict__ row,
    const int* __restrict__ col, const int* __restrict__ blkhist,
    int* __restrict__ bktbase, unsigned* __restrict__ colpart,
    uchar_t* __restrict__ rowpart, int E, int nbkt, int chunk) {
  __shared__ int sbase[400];
  __shared__ int stot[400];
  __shared__ int psum[256];
  __shared__ int sc[400];
  __shared__ int coff[400];
  int t = threadIdx.x, b = blockIdx.x;
  int nrows = 2 * nbkt;
  for (int rr = t; rr < nrows; rr += 256) {
    const int* rp = &blkhist[rr * NBLK];
    int pre = 0, tot = 0;
    for (int i = 0; i < NBLK; ++i) {
      int v = rp[i];
      pre += (i < b) ? v : 0;
      tot += v;
    }
    sbase[rr] = pre; stot[rr] = tot;
  }
  __syncthreads();
  int e0 = (2 * t     < nrows) ? stot[2 * t]     : 0;
  int e1 = (2 * t + 1 < nrows) ? stot[2 * t + 1] : 0;
  psum[t] = e0 + e1;
  __syncthreads();
  for (int off = 1; off < 256; off <<= 1) {
    int add = (t >= off) ? psum[t - off] : 0;
    __syncthreads();
    psum[t] += add;
    __syncthreads();
  }
  int pex = (t == 0) ? 0 : psum[t - 1];
  if (2 * t < nrows)     sc[2 * t]     = pex + sbase[2 * t];
  if (2 * t + 1 < nrows) sc[2 * t + 1] = pex + e0 + sbase[2 * t + 1];
  if (b == 0) {
    if (2 * t < nrows)     bktbase[2 * t]     = pex;
    if (2 * t + 1 < nrows) bktbase[2 * t + 1] = pex + e0;
    if (t == 0) bktbase[nrows] = 2 * E;
  }
  for (int rr = t; rr < nrows; rr += 256) coff[rr] = 0;
  __syncthreads();
  int s = b * chunk, e = min(E, s + chunk);
  for (int i = s + t; i < e; i += 256) {
    unsigned c = (unsigned)col[i], r = (unsigned)row[i];
    int bc = (int)(c >> 8), br = (int)(r >> 8);
    int pc = sc[bc] + atomicAdd(&coff[bc], 1);
    colpart[pc] = (r << 8) | (c & 255u);
    int pr = sc[nbkt + br] + atomicAdd(&coff[nbkt + br], 1) - E;
    rowpart[pr] = (uchar_t)(r & 255u);
  }
}

__global__ __launch_bounds__(256) void bucket_both(const unsigned* __restrict__ colpart,
    const uchar_t* __restrict__ rowpart, const int* __restrict__ bktbase,
    int* __restrict__ col_ptr, int* __restrict__ csr_src, float* __restrict__ nd,
    int N, int E, int nbkt) {
  __shared__ int cnt[256], ex[256], off[256];
  int t = threadIdx.x, bb = blockIdx.x;
  if (bb < nbkt) {
    int bkt = bb;
    int s = bktbase[bkt], e = bktbase[bkt + 1];
    cnt[t] = 0; off[t] = 0;
    __syncthreads();
    for (int i = s + t; i < e; i += 256)
      atomicAdd(&cnt[(int)(colpart[i] & 255u)], 1);
    __syncthreads();
    ex[t] = cnt[t];
    __syncthreads();
    for (int o = 1; o < 256; o <<= 1) {
      int v = (t >= o) ? ex[t - o] : 0;
      __syncthreads();
      ex[t] += v;
      __syncthreads();
    }
    int excl = (t == 0) ? 0 : ex[t - 1];
    __syncthreads();
    ex[t] = excl;
    __syncthreads();
    int node = bkt * 256 + t;
    if (node < N) col_ptr[node] = s + ex[t];
    if (bkt == 0 && t == 0) col_ptr[N] = E;
    for (int i = s + t; i < e; i += 256) {
      unsigned p = colpart[i];
      int lb = (int)(p & 255u);
      int dst = s + ex[lb] + atomicAdd(&off[lb], 1);
      csr_src[dst] = (int)(p >> 8);
    }
  } else {
    int bkt = bb - nbkt;
    int s = bktbase[nbkt + bkt] - E, e = bktbase[nbkt + bkt + 1] - E;
    cnt[t] = 0;
    __syncthreads();
    for (int i = s + t; i < e; i += 256)
      atomicAdd(&cnt[(int)rowpart[i]], 1);
    __syncthreads();
    int node = bkt * 256 + t;
    if (node < N) {
      int d = cnt[t] < 1 ? 1 : cnt[t];
      nd[node] = 1.0f / sqrtf((float)d);
    }
  }
}

// ---------------- GEMM1 (bf16 MFMA) + fused gate0 ----------------

__global__ __launch_bounds__(256) void gemm1_mfma(const float* __restrict__ x,
    const float* __restrict__ w, const float* __restrict__ b,
    const float* __restrict__ gwl, const float* __restrict__ gb,
    const float* __restrict__ nd,
    ushort_t* __restrict__ hbf, float2* __restrict__ pack0,
    float* __restrict__ s2a, int N) {
  __shared__ u32x4 AsBuf[1024];
  __shared__ u32x4 BsBuf[1024];
  char* Asc = (char*)AsBuf;
  char* Bsc = (char*)BsBuf;

  int t = threadIdx.x;
  int lane = t & 63;
  int wid = t >> 6;
  int wm = wid >> 1;
  int wn = wid & 1;
  int m0 = blockIdx.x * 128;
  int ql = lane & 15;

  f32x4 acc[4][4];
#pragma unroll
  for (int i = 0; i < 4; ++i)
#pragma unroll
    for (int j = 0; j < 4; ++j) acc[i][j] = (f32x4){0.f, 0.f, 0.f, 0.f};

  float bias[4], g1v[4], g2v[4];
#pragma unroll
  for (int j = 0; j < 4; ++j) {
    int c = wn * 64 + j * 16 + ql;
    bias[j] = b[c];
    g1v[j] = gwl[c];
    g2v[j] = gwl[H_DIM + c];
  }

  for (int kk = 0; kk < F_DIM; kk += 64) {
#pragma unroll
    for (int q = 0; q < 4; ++q) {
      int c = q * 256 + t;
      int row = c >> 3, kc = c & 7;
      int gm = m0 + row;
      f32x4 v0 = {0.f, 0.f, 0.f, 0.f}, v1 = {0.f, 0.f, 0.f, 0.f};
      if (gm < N) {
        const float* src = &x[(size_t)gm * F_DIM + kk + kc * 8];
        v0 = *(const f32x4*)src;
        v1 = *(const f32x4*)(src + 4);
      }
      u32x4 pk;
      pk[0] = pack2bf(v0[0], v0[1]);
      pk[1] = pack2bf(v0[2], v0[3]);
      pk[2] = pack2bf(v1[0], v1[1]);
      pk[3] = pack2bf(v1[2], v1[3]);
      *(u32x4*)(Asc + row * 128 + ((kc ^ (row & 7)) << 4)) = pk;
    }
#pragma unroll
    for (int q = 0; q < 4; ++q) {
      int c = q * 256 + t;
      int row = c >> 3, kc = c & 7;
      const float* src = &w[(size_t)row * F_DIM + kk + kc * 8];
      f32x4 v0 = *(const f32x4*)src;
      f32x4 v1 = *(const f32x4*)(src + 4);
      u32x4 pk;
      pk[0] = pack2bf(v0[0], v0[1]);
      pk[1] = pack2bf(v0[2], v0[3]);
      pk[2] = pack2bf(v1[0], v1[1]);
      pk[3] = pack2bf(v1[2], v1[3]);
      *(u32x4*)(Bsc + row * 128 + ((kc ^ (row & 7)) << 4)) = pk;
    }
    __syncthreads();
#pragma unroll
    for (int kh = 0; kh < 2; ++kh) {
      bf16x8 af[4], bfr[4];
      int kc = kh * 4 + (lane >> 4);
#pragma unroll
      for (int i = 0; i < 4; ++i) {
        int row = wm * 64 + i * 16 + ql;
        af[i] = *(const bf16x8*)(Asc + row * 128 + ((kc ^ (row & 7)) << 4));
      }
#pragma unroll
      for (int j = 0; j < 4; ++j) {
        int row = wn * 64 + j * 16 + ql;
        bfr[j] = *(const bf16x8*)(Bsc + row * 128 + ((kc ^ (row & 7)) << 4));
      }
#pragma unroll
      for (int i = 0; i < 4; ++i)
#pragma unroll
        for (int j = 0; j < 4; ++j)
          acc[i][j] = __builtin_amdgcn_mfma_f32_16x16x32_bf16(af[i], bfr[j], acc[i][j], 0, 0, 0);
    }
    __syncthreads();
  }

  float gp1[4][4], gp2[4][4];
#pragma unroll
  for (int i = 0; i < 4; ++i)
#pragma unroll
    for (int r = 0; r < 4; ++r) { gp1[i][r] = 0.f; gp2[i][r] = 0.f; }

#pragma unroll
  for (int i = 0; i < 4; ++i) {
    int rbase = m0 + wm * 64 + i * 16 + ((lane >> 4) * 4);
#pragma unroll
    for (int j = 0; j < 4; ++j) {
      int col = wn * 64 + j * 16 + ql;
#pragma unroll
      for (int r = 0; r < 4; ++r) {
        int gr = rbase + r;
        float o = fmaxf(acc[i][j][r] + bias[j], 0.f);
        if (gr < N) hbf[(size_t)gr * H_DIM + col] = f2bf(o);
        gp1[i][r] = fmaf(o, g1v[j], gp1[i][r]);
        gp2[i][r] = fmaf(o, g2v[j], gp2[i][r]);
      }
    }
  }
#pragma unroll
  for (int i = 0; i < 4; ++i)
#pragma unroll
    for (int r = 0; r < 4; ++r) {
#pragma unroll
      for (int m = 1; m < 16; m <<= 1) {
        gp1[i][r] += __shfl_xor(gp1[i][r], m);
        gp2[i][r] += __shfl_xor(gp2[i][r], m);
      }
    }
  float* pgA = (float*)AsBuf;
  float* pgB = (float*)AsBuf + 256;
  if (ql == 0) {
#pragma unroll
    for (int i = 0; i < 4; ++i)
#pragma unroll
      for (int r = 0; r < 4; ++r) {
        int lr = wm * 64 + i * 16 + (lane >> 4) * 4 + r;
        pgA[lr * 2 + wn] = gp1[i][r];
        pgB[lr * 2 + wn] = gp2[i][r];
      }
  }
  __syncthreads();
  if (t < 128) {
    int gr = m0 + t;
    if (gr < N) {
      float p1 = pgA[t * 2] + pgA[t * 2 + 1];
      float p2 = pgB[t * 2] + pgB[t * 2 + 1];
      float ndv = nd[gr];
      pack0[gr] = make_float2(p1, ndv);
      s2a[gr] = p2 + gb[0];
    }
  }
}

// ---------------- aggregation core: 64-lane u32 row gathers, MLP=8 ----------------
// Each wave owns one target node v. Lane holds columns (2*lane, 2*lane+1).

#define AGG_CORE(HSRC)                                                          \
  float ax = 0.f, ay = 0.f;                                                     \
  {                                                                             \
    int p0 = col_ptr[v], p1v = col_ptr[v + 1];                                  \
    float s2v = s2pb[v];                                                        \
    for (int base = p0; base < p1v; base += 64) {                               \
      int idx = base + lane;                                                    \
      int u = 0;                                                                \
      float cf = 0.f;                                                           \
      if (idx < p1v) {                                                          \
        u = csr_src[idx];                                                       \
        float2 pk = pack[u];                                                    \
        cf = fast_tanh(pk.x + s2v) * pk.y * ndv;                                \
      }                                                                         \
      int cnt = p1v - base;                                                     \
      if (cnt > 64) cnt = 64;                                                   \
      int j = 0;                                                                \
      for (; j + 8 <= cnt; j += 8) {                                            \
        int u0 = __shfl(u, j + 0), u1 = __shfl(u, j + 1);                       \
        int u2 = __shfl(u, j + 2), u3 = __shfl(u, j + 3);                       \
        int u4 = __shfl(u, j + 4), u5 = __shfl(u, j + 5);                       \
        int u6 = __shfl(u, j + 6), u7 = __shfl(u, j + 7);                       \
        unsigned t0 = *(const unsigned*)&HSRC[(size_t)u0 * H_DIM + lane * 2];   \
        unsigned t1 = *(const unsigned*)&HSRC[(size_t)u1 * H_DIM + lane * 2];   \
        unsigned t2 = *(const unsigned*)&HSRC[(size_t)u2 * H_DIM + lane * 2];   \
        unsigned t3 = *(const unsigned*)&HSRC[(size_t)u3 * H_DIM + lane * 2];   \
        unsigned t4 = *(const unsigned*)&HSRC[(size_t)u4 * H_DIM + lane * 2];   \
        unsigned t5 = *(const unsigned*)&HSRC[(size_t)u5 * H_DIM + lane * 2];   \
        unsigned t6 = *(const unsigned*)&HSRC[(size_t)u6 * H_DIM + lane * 2];   \
        unsigned t7 = *(const unsigned*)&HSRC[(size_t)u7 * H_DIM + lane * 2];   \
        float c0 = __shfl(cf, j + 0), c1 = __shfl(cf, j + 1);                   \
        float c2 = __shfl(cf, j + 2), c3 = __shfl(cf, j + 3);                   \
        float c4 = __shfl(cf, j + 4), c5 = __shfl(cf, j + 5);                   \
        float c6 = __shfl(cf, j + 6), c7 = __shfl(cf, j + 7);                   \
        ax = fmaf(c0, bflo(t0), ax); ay = fmaf(c0, bfhi(t0), ay);               \
        ax = fmaf(c1, bflo(t1), ax); ay = fmaf(c1, bfhi(t1), ay);               \
        ax = fmaf(c2, bflo(t2), ax); ay = fmaf(c2, bfhi(t2), ay);               \
        ax = fmaf(c3, bflo(t3), ax); ay = fmaf(c3, bfhi(t3), ay);               \
        ax = fmaf(c4, bflo(t4), ax); ay = fmaf(c4, bfhi(t4), ay);               \
        ax = fmaf(c5, bflo(t5), ax); ay = fmaf(c5, bfhi(t5), ay);               \
        ax = fmaf(c6, bflo(t6), ax); ay = fmaf(c6, bfhi(t6), ay);               \
        ax = fmaf(c7, bflo(t7), ax); ay = fmaf(c7, bfhi(t7), ay);               \
      }                                                                         \
      for (; j + 4 <= cnt; j += 4) {                                            \
        int u0 = __shfl(u, j + 0), u1 = __shfl(u, j + 1);                       \
        int u2 = __shfl(u, j + 2), u3 = __shfl(u, j + 3);                       \
        unsigned t0 = *(const unsigned*)&HSRC[(size_t)u0 * H_DIM + lane * 2];   \
        unsigned t1 = *(const unsigned*)&HSRC[(size_t)u1 * H_DIM + lane * 2];   \
        unsigned t2 = *(const unsigned*)&HSRC[(size_t)u2 * H_DIM + lane * 2];   \
        unsigned t3 = *(const unsigned*)&HSRC[(size_t)u3 * H_DIM + lane * 2];   \
        float c0 = __shfl(cf, j + 0), c1 = __shfl(cf, j + 1);                   \
        float c2 = __shfl(cf, j + 2), c3 = __shfl(cf, j + 3);                   \
        ax = fmaf(c0, bflo(t0), ax); ay = fmaf(c0, bfhi(t0), ay);               \
        ax = fmaf(c1, bflo(t1), ax); ay = fmaf(c1, bfhi(t1), ay);               \
        ax = fmaf(c2, bflo(t2), ax); ay = fmaf(c2, bfhi(t2), ay);               \
        ax = fmaf(c3, bflo(t3), ax); ay = fmaf(c3, bfhi(t3), ay);               \
      }                                                                         \
      for (; j < cnt; ++j) {                                                    \
        int uj = __shfl(u, j);                                                  \
        float cj = __shfl(cf, j);                                               \
        unsigned tj = *(const unsigned*)&HSRC[(size_t)uj * H_DIM + lane * 2];   \
        ax = fmaf(cj, bflo(tj), ax); ay = fmaf(cj, bfhi(tj), ay);               \
      }                                                                         \
    }                                                                           \
  }

// agg layer 1: h1 = EPS*h0 + agg(h0); fused gate1 -> pack1, s2b.  Zero LDS.
__global__ __launch_bounds__(256) void agg1(const ushort_t* __restrict__ hbf,
    const float2* __restrict__ pack, const float* __restrict__ s2pb,
    const float* __restrict__ nd, const int* __restrict__ col_ptr,
    const int* __restrict__ csr_src, ushort_t* __restrict__ houtbf,
    const float* __restrict__ gwl, const float* __restrict__ gb1,
    float2* __restrict__ packo, float* __restrict__ s2o, int N) {
  int t = threadIdx.x;
  int v = blockIdx.x * 4 + (t >> 6);
  int lane = t & 63;
  if (v >= N) return;
  float ndv = nd[v];
  unsigned rv = *(const unsigned*)&hbf[(size_t)v * H_DIM + lane * 2];  // raw = h0
  AGG_CORE(hbf)
  float ox = fmaf(EPS_F, bflo(rv), ax);
  float oy = fmaf(EPS_F, bfhi(rv), ay);
  *(unsigned*)&houtbf[(size_t)v * H_DIM + lane * 2] = pack2bf(ox, oy);
  // fused gate for layer 1
  float2 g1 = *(const float2*)&gwl[lane * 2];
  float2 g2 = *(const float2*)&gwl[H_DIM + lane * 2];
  float q1 = ox * g1.x + oy * g1.y;
  float q2 = ox * g2.x + oy * g2.y;
#pragma unroll
  for (int off = 32; off > 0; off >>= 1) {
    q1 += __shfl_xor(q1, off);
    q2 += __shfl_xor(q2, off);
  }
  if (lane == 0) {
    packo[v] = make_float2(q1, ndv);
    s2o[v] = q2 + gb1[0];
  }
}

// agg layer 2 + fused gemm2 + log_softmax
__global__ __launch_bounds__(256) void agg2(const ushort_t* __restrict__ hbf,
    const ushort_t* __restrict__ rawbf, const float2* __restrict__ pack,
    const float* __restrict__ s2pb, const float* __restrict__ nd,
    const int* __restrict__ col_ptr, const int* __restrict__ csr_src,
    const float* __restrict__ w2, const float* __restrict__ b2,
    float* __restrict__ out, int N) {
  __shared__ float ws[C_DIM][129];
  __shared__ float bsh[C_DIM];
  __shared__ float hsm[4][H_DIM];
  int t = threadIdx.x;
  for (int i = t; i < C_DIM * H_DIM; i += 256) ws[i / H_DIM][i % H_DIM] = w2[i];
  if (t < C_DIM) bsh[t] = b2[t];
  __syncthreads();
  int wave = t >> 6, lane = t & 63;
  int v = blockIdx.x * 4 + wave;
  bool act = v < N;
  float ox = 0.f, oy = 0.f;
  if (act) {
    float ndv = nd[v];
    unsigned rv = *(const unsigned*)&rawbf[(size_t)v * H_DIM + lane * 2];
    AGG_CORE(hbf)
    ox = fmaf(EPS_F, bflo(rv), ax);
    oy = fmaf(EPS_F, bfhi(rv), ay);
    hsm[wave][lane * 2] = ox;
    hsm[wave][lane * 2 + 1] = oy;
  }
  __syncthreads();
  float accv = 0.f;
  if (act && lane < C_DIM) {
#pragma unroll 8
    for (int k = 0; k < H_DIM; ++k)
      accv = fmaf(hsm[wave][k], ws[lane][k], accv);
    accv += bsh[lane];
  }
  float m = (lane < C_DIM) ? accv : -1e30f;
#pragma unroll
  for (int off = 32; off > 0; off >>= 1) m = fmaxf(m, __shfl_xor(m, off));
  float ex = (lane < C_DIM) ? expf(accv - m) : 0.f;
  float s = ex;
#pragma unroll
  for (int off = 32; off > 0; off >>= 1) s += __shfl_xor(s, off);
  float lse = m + logf(s);
  if (act && lane < C_DIM) out[(size_t)v * C_DIM + lane] = accv - lse;
}

// ---------------- launch ----------------

extern "C" void kernel_launch(void* const* d_in, const int* in_sizes, int n_in,
                              void* d_out, int out_size, void* d_ws, size_t ws_size,
                              hipStream_t stream) {
  const float* x   = (const float*)d_in[0];
  const float* t1w = (const float*)d_in[1];
  const float* t1b = (const float*)d_in[2];
  const float* t2w = (const float*)d_in[3];
  const float* t2b = (const float*)d_in[4];
  const float* gw  = (const float*)d_in[5];
  const float* gb  = (const float*)d_in[6];
  const int*   ei  = (const int*)d_in[7];
  const int N = in_sizes[0] / F_DIM;
  const int E = in_sizes[7] / 2;
  float* out = (float*)d_out;

  char* p = (char*)d_ws;
  auto take = [&](size_t bytes) {
    char* r = p;
    p += (bytes + 255) & ~(size_t)255;
    return r;
  };
  ushort_t* h0 = (ushort_t*)take((size_t)N * H_DIM * 2);
  ushort_t* h1 = (ushort_t*)take((size_t)N * H_DIM * 2);
  float2* pack0 = (float2*)take((size_t)N * 8);
  float2* pack1 = (float2*)take((size_t)N * 8);
  float* s2a = (float*)take((size_t)N * 4);
  float* s2b = (float*)take((size_t)N * 4);
  float* nd  = (float*)take((size_t)N * 4);
  int* col_ptr = (int*)take((size_t)(N + 1) * 4);
  int* csr_src = (int*)take((size_t)E * 4);

  const int nbkt = (N + 255) >> 8;              // 196
  const int chunk = (E + NBLK - 1) / NBLK;      // 3125

  int* blkhist = (int*)take((size_t)2 * nbkt * NBLK * 4);
  int* bktbase = (int*)take((size_t)(2 * nbkt + 1) * 4);
  unsigned* colpart = (unsigned*)take((size_t)E * 4);
  uchar_t* rowpart  = (uchar_t*)take((size_t)E);

  const int* row = ei;
  const int* col = ei + E;

  part_count<<<NBLK, 256, 0, stream>>>(row, col, blkhist, E, nbkt, chunk);
  part_scatter<<<NBLK, 256, 0, stream>>>(row, col, blkhist, bktbase, colpart, rowpart, E, nbkt, chunk);
  bucket_both<<<2 * nbkt, 256, 0, stream>>>(colpart, rowpart, bktbase, col_ptr, csr_src, nd, N, E, nbkt);

  gemm1_mfma<<<(N + 127) / 128, 256, 0, stream>>>(x, t1w, t1b, gw, gb, nd, h0, pack0, s2a, N);

  int nwb = (N + 3) / 4;
  agg1<<<nwb, 256, 0, stream>>>(h0, pack0, s2a, nd, col_ptr, csr_src, h1,
                                gw + 2 * H_DIM, gb + 1, pack1, s2b, N);
  agg2<<<nwb, 256, 0, stream>>>(h1, h0, pack1, s2b, nd, col_ptr, csr_src,
                                t2w, t2b, out, N);
}